// Round 6
// baseline (1377.251 us; speedup 1.0000x reference)
//
#include <hip/hip_runtime.h>

#define DEV __global__ __launch_bounds__(256)

constexpr int NN = 50000;   // nodes
constexpr int NE = 600000;  // edges
constexpr int D  = 128;     // emb dim
constexpr int NG = 500;     // graphs
constexpr int NL = 3;       // layers
constexpr int SCAN_B = 512;
constexpr int NBLK = (NN + SCAN_B - 1) / SCAN_B;  // 98

typedef __attribute__((ext_vector_type(8))) short bf16x8;
typedef __attribute__((ext_vector_type(4))) float f32x4;

__device__ inline ushort f2bf(float f) {
  unsigned u = __builtin_bit_cast(unsigned, f);
  unsigned r = u + 0x7FFFu + ((u >> 16) & 1u);
  return (ushort)(r >> 16);
}
__device__ inline float bf2f(ushort h) {
  unsigned u = ((unsigned)h) << 16;
  return __builtin_bit_cast(float, u);
}

// ---------------- encoders / elementwise ----------------

// hv0[n][d] = sum_i atom_emb[i][x[n][i]][d] + vn_emb[d]
DEV void k_atom(const int* __restrict__ x, const float* __restrict__ emb,
                const float* __restrict__ vne, float* __restrict__ hv) {
  int t = blockIdx.x * 256 + threadIdx.x;
  int n = t >> 5, c = (t & 31) * 4;
  if (n >= NN) return;
  float4 acc = *(const float4*)(vne + c);
  #pragma unroll
  for (int i = 0; i < 9; ++i) {
    int v = x[n * 9 + i];
    float4 e = *(const float4*)(emb + ((size_t)(i * 128 + v)) * D + c);
    acc.x += e.x; acc.y += e.y; acc.z += e.z; acc.w += e.w;
  }
  *(float4*)(hv + (size_t)n * D + c) = acc;
}

DEV void k_vninit(const float* __restrict__ src, float* __restrict__ vn) {
  int t = blockIdx.x * 256 + threadIdx.x;
  int g = t >> 5, c = (t & 31) * 4;
  if (g >= NG) return;
  *(float4*)(vn + (size_t)g * D + c) = *(const float4*)(src + c);
}

// dst = bn(z) [+relu] [+ vnadd[batch]]   (stats computed inline from sum/sq)
DEV void k_post(const float* __restrict__ z, const float* __restrict__ sum,
                const float* __restrict__ sq, const float* __restrict__ gam,
                const float* __restrict__ bet, float invM,
                const float* __restrict__ vnadd, const int* __restrict__ batch,
                float* __restrict__ dst, int M, int relu) {
  int t = blockIdx.x * 256 + threadIdx.x;
  int n = t >> 5, c = (t & 31) * 4;
  if (n >= M) return;
  f32x4 s = *(const f32x4*)(sum + c);
  f32x4 q = *(const f32x4*)(sq + c);
  f32x4 g = *(const f32x4*)(gam + c);
  f32x4 b = *(const f32x4*)(bet + c);
  f32x4 v = *(const f32x4*)(z + (size_t)n * 128 + c);
  f32x4 o;
  #pragma unroll
  for (int j = 0; j < 4; ++j) {
    float mu = s[j] * invM;
    float var = q[j] * invM - mu * mu;
    float sc = g[j] * rsqrtf(var + 1e-5f);
    float sh = b[j] - mu * sc;
    o[j] = fmaf(v[j], sc, sh);
    if (relu) o[j] = fmaxf(o[j], 0.f);
  }
  if (vnadd) {
    f32x4 a = *(const f32x4*)(vnadd + (size_t)batch[n] * 128 + c);
    #pragma unroll
    for (int j = 0; j < 4; ++j) o[j] += a[j];
  }
  *(f32x4*)(dst + (size_t)n * 128 + c) = o;
}

// ---------------- CSR build ----------------

DEV void k_hist(const int* __restrict__ ei, int* __restrict__ cnt) {
  int e = blockIdx.x * 256 + threadIdx.x;
  if (e < NE) atomicAdd(&cnt[ei[NE + e]], 1);
}

__global__ __launch_bounds__(SCAN_B) void k_scan_a(const int* __restrict__ cnt,
                                                   int* __restrict__ rowptr,
                                                   int* __restrict__ bsum) {
  __shared__ int sh[SCAN_B];
  int i = blockIdx.x * SCAN_B + threadIdx.x;
  int v = (i < NN) ? cnt[i] : 0;
  sh[threadIdx.x] = v;
  __syncthreads();
  for (int off = 1; off < SCAN_B; off <<= 1) {
    int u = (threadIdx.x >= (unsigned)off) ? sh[threadIdx.x - off] : 0;
    __syncthreads();
    sh[threadIdx.x] += u;
    __syncthreads();
  }
  if (i < NN) rowptr[i + 1] = sh[threadIdx.x];
  if (threadIdx.x == SCAN_B - 1) bsum[blockIdx.x] = sh[SCAN_B - 1];
}

__global__ void k_scan_b(int* __restrict__ bsum, int nb) {
  if (threadIdx.x == 0 && blockIdx.x == 0) {
    int acc = 0;
    for (int i = 0; i < nb; ++i) { int v = bsum[i]; bsum[i] = acc; acc += v; }
  }
}

__global__ __launch_bounds__(SCAN_B) void k_scan_c(int* __restrict__ rowptr,
                                                   const int* __restrict__ bsum) {
  int i = blockIdx.x * SCAN_B + threadIdx.x;
  if (i < NN) rowptr[i + 1] += bsum[blockIdx.x];
  if (i == 0) rowptr[0] = 0;
}

DEV void k_fill(const int* __restrict__ ei, const int* __restrict__ eattr,
                int* __restrict__ cursor, unsigned* __restrict__ csr) {
  int e = blockIdx.x * 256 + threadIdx.x;
  if (e >= NE) return;
  int dn = ei[NE + e];
  int p = atomicAdd(&cursor[dn], 1);
  unsigned a0 = (unsigned)eattr[e * 3 + 0];
  unsigned a1 = (unsigned)eattr[e * 3 + 1];
  unsigned a2 = (unsigned)eattr[e * 3 + 2];
  csr[p] = (unsigned)ei[e] | (a0 << 17) | (a1 << 20) | (a2 << 23);
}

// ---- edge aggregation (wave per node) + fused A' = (1+eps)*hv + agg,
//      written pre-split as bf16 hi/lo planes ready for MFMA staging ----

DEV void k_agg(const float* __restrict__ hv, const unsigned* __restrict__ csr,
               const int* __restrict__ rowptr, const float* __restrict__ bond,
               const float* __restrict__ epsp, unsigned* __restrict__ Ahi,
               unsigned* __restrict__ Alo) {
  __shared__ float eb[3 * 8 * D];
  for (int i = threadIdx.x; i < 3 * 8 * D; i += 256) eb[i] = bond[i];
  __syncthreads();
  int wid = (blockIdx.x * 256 + threadIdx.x) >> 6;
  int lane = threadIdx.x & 63;
  if (wid >= NN) return;
  int d0 = lane * 2;
  float ax = 0.f, ay = 0.f;
  int p = rowptr[wid];
  const int p1 = rowptr[wid + 1];
  for (; p + 4 <= p1; p += 4) {
    unsigned pk[4];
    #pragma unroll
    for (int j = 0; j < 4; ++j) pk[j] = csr[p + j];
    float2 hvv[4];
    #pragma unroll
    for (int j = 0; j < 4; ++j)
      hvv[j] = *(const float2*)(hv + (size_t)(pk[j] & 0x1FFFF) * D + d0);
    #pragma unroll
    for (int j = 0; j < 4; ++j) {
      float2 e0 = *(const float2*)(eb + (((pk[j] >> 17) & 7u)) * D + d0);
      float2 e1 = *(const float2*)(eb + (8 + ((pk[j] >> 20) & 7u)) * D + d0);
      float2 e2 = *(const float2*)(eb + (16 + ((pk[j] >> 23) & 7u)) * D + d0);
      ax += fmaxf(hvv[j].x + e0.x + e1.x + e2.x, 0.f);
      ay += fmaxf(hvv[j].y + e0.y + e1.y + e2.y, 0.f);
    }
  }
  for (; p < p1; ++p) {
    unsigned pk = csr[p];
    float2 hvv = *(const float2*)(hv + (size_t)(pk & 0x1FFFF) * D + d0);
    float2 e0 = *(const float2*)(eb + (((pk >> 17) & 7u)) * D + d0);
    float2 e1 = *(const float2*)(eb + (8 + ((pk >> 20) & 7u)) * D + d0);
    float2 e2 = *(const float2*)(eb + (16 + ((pk >> 23) & 7u)) * D + d0);
    ax += fmaxf(hvv.x + e0.x + e1.x + e2.x, 0.f);
    ay += fmaxf(hvv.y + e0.y + e1.y + e2.y, 0.f);
  }
  // fused mgemm1 prologue: A' = (1+eps)*hv + agg, split exact bf16 hi/lo
  float2 hvo = *(const float2*)(hv + (size_t)wid * D + d0);
  float ef = 1.f + epsp[0];
  float a0 = fmaf(ef, hvo.x, ax);
  float a1 = fmaf(ef, hvo.y, ay);
  ushort h0 = f2bf(a0), h1 = f2bf(a1);
  ushort l0 = f2bf(a0 - bf2f(h0)), l1 = f2bf(a1 - bf2f(h1));
  Ahi[(size_t)wid * 64 + lane] = (unsigned)h0 | ((unsigned)h1 << 16);
  Alo[(size_t)wid * 64 + lane] = (unsigned)l0 | ((unsigned)l1 << 16);
}

// ---------------- weight transpose + bf16 hi/lo split ----------------
// src fp32 [L][K][NC] -> th/tl bf16 [L][NC][K]
__global__ __launch_bounds__(256) void k_cvtw(const float* __restrict__ src, int K,
                                              int lognc, ushort* __restrict__ th,
                                              ushort* __restrict__ tl) {
  int NC = 1 << lognc;
  size_t base = (size_t)blockIdx.y * K * NC;
  int i = blockIdx.x * 256 + threadIdx.x;
  if (i >= K * NC) return;
  int k = i >> lognc, c = i & (NC - 1);
  float v = src[base + i];
  ushort hi = f2bf(v);
  th[base + (size_t)c * K + k] = hi;
  tl[base + (size_t)c * K + k] = f2bf(v - bf2f(hi));
}

// ---------------- MFMA bf16x3 GEMM + BN-stats epilogue ----------------
// Y[M x COLS] = A' @ Wt^T + bias
//   AMODE 0: A' = A0 (fp32, split on the fly)
//   AMODE 2: A' = relu(A0 * bnscale[k] + bnshift[k])  (scale/shift from sum/sq)
//   AMODE 3: A' pre-split bf16 planes Ath/Atl (pure copy staging)
// Stats: ATOMIC -> atomicAdd into colsum/colsq; else per-block partials.
template <int AMODE, int COLS, int NT, bool ATOMIC>
__global__ __launch_bounds__(NT) void k_mgemm(
    int M, int K, const float* __restrict__ A0, const ushort* __restrict__ Ath,
    const ushort* __restrict__ Atl, const float* __restrict__ bnsum,
    const float* __restrict__ bnsq, const float* __restrict__ bngam,
    const float* __restrict__ bnbet, float invPrevM,
    const ushort* __restrict__ Wth, const ushort* __restrict__ Wtl,
    const float* __restrict__ bias, float* __restrict__ Y,
    float* __restrict__ colsum, float* __restrict__ colsq,
    float* __restrict__ partial) {
  constexpr int NWC = COLS / 64;
  __shared__ __align__(16) ushort Ah[4][128][8];
  __shared__ __align__(16) ushort Al[4][128][8];
  __shared__ __align__(16) ushort Bh[4][COLS][8];
  __shared__ __align__(16) ushort Bl[4][COLS][8];
  __shared__ float bnsc[AMODE == 2 ? 256 : 1];
  __shared__ float bnsh[AMODE == 2 ? 256 : 1];
  const int tid = threadIdx.x;
  const int row0 = blockIdx.x * 128;
  const int lane = tid & 63, w = tid >> 6;
  const int wr = w / NWC, wc = w % NWC;
  const int kc = lane >> 4, lr = lane & 15;

  if (AMODE == 2) {
    for (int c = tid; c < K; c += NT) {
      float mu = bnsum[c] * invPrevM;
      float var = bnsq[c] * invPrevM - mu * mu;
      float sc = bngam[c] * rsqrtf(var + 1e-5f);
      bnsc[c] = sc;
      bnsh[c] = bnbet[c] - mu * sc;
    }
    __syncthreads();
  }

  f32x4 acc[4][4] = {};

  for (int k0 = 0; k0 < K; k0 += 32) {
    // ---- stage A' ----
    for (int i = tid; i < 512; i += NT) {
      const int c = i >> 7, r = i & 127;
      const int gk = k0 + c * 8;
      const int gr = row0 + r;
      if (AMODE == 3) {
        uint4 vh = make_uint4(0, 0, 0, 0), vl = make_uint4(0, 0, 0, 0);
        if (gr < M) {
          vh = *(const uint4*)(Ath + (size_t)gr * K + gk);
          vl = *(const uint4*)(Atl + (size_t)gr * K + gk);
        }
        *(uint4*)&Ah[c][r][0] = vh;
        *(uint4*)&Al[c][r][0] = vl;
      } else {
        float v[8];
        if (gr < M) {
          f32x4 a0 = *(const f32x4*)(A0 + (size_t)gr * K + gk);
          f32x4 a1 = *(const f32x4*)(A0 + (size_t)gr * K + gk + 4);
          if (AMODE == 2) {
            f32x4 s0 = *(const f32x4*)&bnsc[gk];
            f32x4 s1 = *(const f32x4*)&bnsc[gk + 4];
            f32x4 t0 = *(const f32x4*)&bnsh[gk];
            f32x4 t1 = *(const f32x4*)&bnsh[gk + 4];
            #pragma unroll
            for (int j = 0; j < 4; ++j) {
              v[j] = fmaxf(fmaf(a0[j], s0[j], t0[j]), 0.f);
              v[4 + j] = fmaxf(fmaf(a1[j], s1[j], t1[j]), 0.f);
            }
          } else {
            #pragma unroll
            for (int j = 0; j < 4; ++j) { v[j] = a0[j]; v[4 + j] = a1[j]; }
          }
        } else {
          #pragma unroll
          for (int j = 0; j < 8; ++j) v[j] = 0.f;
        }
        alignas(16) ushort th[8], tl[8];
        #pragma unroll
        for (int j = 0; j < 8; ++j) {
          ushort hi = f2bf(v[j]);
          th[j] = hi;
          tl[j] = f2bf(v[j] - bf2f(hi));
        }
        *(uint4*)&Ah[c][r][0] = *(const uint4*)th;
        *(uint4*)&Al[c][r][0] = *(const uint4*)tl;
      }
    }
    // ---- stage B ----
    for (int i = tid; i < COLS * 4; i += NT) {
      const int c = i / COLS, r = i % COLS;
      const int gk = k0 + c * 8;
      *(uint4*)&Bh[c][r][0] = *(const uint4*)(Wth + (size_t)r * K + gk);
      *(uint4*)&Bl[c][r][0] = *(const uint4*)(Wtl + (size_t)r * K + gk);
    }
    __syncthreads();
    // ---- MFMA: 3-term bf16 emulation of fp32 ----
    bf16x8 bhf[4], blf[4];
    #pragma unroll
    for (int fc = 0; fc < 4; ++fc) {
      bhf[fc] = *(const bf16x8*)&Bh[kc][wc * 64 + fc * 16 + lr][0];
      blf[fc] = *(const bf16x8*)&Bl[kc][wc * 64 + fc * 16 + lr][0];
    }
    #pragma unroll
    for (int fr = 0; fr < 4; ++fr) {
      bf16x8 ahf = *(const bf16x8*)&Ah[kc][wr * 64 + fr * 16 + lr][0];
      bf16x8 alf = *(const bf16x8*)&Al[kc][wr * 64 + fr * 16 + lr][0];
      #pragma unroll
      for (int fc = 0; fc < 4; ++fc) {
        acc[fr][fc] = __builtin_amdgcn_mfma_f32_16x16x32_bf16(ahf, bhf[fc], acc[fr][fc], 0, 0, 0);
        acc[fr][fc] = __builtin_amdgcn_mfma_f32_16x16x32_bf16(alf, bhf[fc], acc[fr][fc], 0, 0, 0);
        acc[fr][fc] = __builtin_amdgcn_mfma_f32_16x16x32_bf16(ahf, blf[fc], acc[fr][fc], 0, 0, 0);
      }
    }
    __syncthreads();
  }

  // ---- epilogue: bias, store, block-level column stats (no global atomics) ----
  float* sred = reinterpret_cast<float*>(&Ah[0][0][0]);  // [2][COLS] (Ah is dead)
  float* qred = sred + 2 * COLS;
  #pragma unroll
  for (int fc = 0; fc < 4; ++fc) {
    const int gc = wc * 64 + fc * 16 + lr;
    const float bb = bias[gc];
    float cs = 0.f, cq = 0.f;
    #pragma unroll
    for (int fr = 0; fr < 4; ++fr) {
      const int rb = row0 + wr * 64 + fr * 16 + kc * 4;
      #pragma unroll
      for (int rg = 0; rg < 4; ++rg) {
        int gr = rb + rg;
        if (gr < M) {
          float v = acc[fr][fc][rg] + bb;
          Y[(size_t)gr * COLS + gc] = v;
          cs += v;
          cq += v * v;
        }
      }
    }
    cs += __shfl_xor(cs, 16); cs += __shfl_xor(cs, 32);
    cq += __shfl_xor(cq, 16); cq += __shfl_xor(cq, 32);
    if (kc == 0) {
      sred[wr * COLS + gc] = cs;
      qred[wr * COLS + gc] = cq;
    }
  }
  __syncthreads();
  for (int c = tid; c < COLS; c += NT) {
    float s = sred[c] + sred[COLS + c];
    float q = qred[c] + qred[COLS + c];
    if (ATOMIC) {
      atomicAdd(&colsum[c], s);
      atomicAdd(&colsq[c], q);
    } else {
      partial[(size_t)blockIdx.x * 2 * COLS + c] = s;
      partial[(size_t)blockIdx.x * 2 * COLS + COLS + c] = q;
    }
  }
}

// sum partials over blocks -> SUM/SQ
__global__ __launch_bounds__(256) void k_red(const float* __restrict__ part, int nb,
                                             int width, float* __restrict__ outSum,
                                             float* __restrict__ outSq) {
  int j = blockIdx.x * 256 + threadIdx.x;
  if (j >= 2 * width) return;
  float a = 0.f;
  for (int b = 0; b < nb; ++b) a += part[(size_t)b * 2 * width + j];
  if (j < width) outSum[j] = a;
  else outSq[j - width] = a;
}

// ---------------- graph pooling ----------------

DEV void k_pool(const float* __restrict__ hv, const int* __restrict__ batch,
                const float* __restrict__ vn, float* __restrict__ vt) {
  int g = blockIdx.x;
  int lo = 0, hi = NN;
  while (lo < hi) { int mid = (lo + hi) >> 1; if (batch[mid] < g) lo = mid + 1; else hi = mid; }
  int s = lo;
  hi = NN;
  while (lo < hi) { int mid = (lo + hi) >> 1; if (batch[mid] < g + 1) lo = mid + 1; else hi = mid; }
  int e = lo;
  int ry = threadIdx.x >> 5, cx = threadIdx.x & 31;
  float4 acc = make_float4(0.f, 0.f, 0.f, 0.f);
  for (int n = s + ry; n < e; n += 8) {
    float4 v = *(const float4*)(hv + (size_t)n * D + cx * 4);
    acc.x += v.x; acc.y += v.y; acc.z += v.z; acc.w += v.w;
  }
  __shared__ float4 red[8][32];
  red[ry][cx] = acc;
  __syncthreads();
  for (int st = 4; st >= 1; st >>= 1) {
    if (ry < st) {
      float4 o = red[ry + st][cx];
      red[ry][cx].x += o.x; red[ry][cx].y += o.y;
      red[ry][cx].z += o.z; red[ry][cx].w += o.w;
    }
    __syncthreads();
  }
  if (ry == 0) {
    float4 v = red[0][cx];
    float4 b = *(const float4*)(vn + (size_t)g * D + cx * 4);
    v.x += b.x; v.y += b.y; v.z += b.z; v.w += b.w;
    *(float4*)(vt + (size_t)g * D + cx * 4) = v;
  }
}

// ---------------- launcher ----------------

extern "C" void kernel_launch(void* const* d_in, const int* in_sizes, int n_in,
                              void* d_out, int out_size, void* d_ws, size_t ws_size,
                              hipStream_t stream) {
  const int* x = (const int*)d_in[0];
  const int* ei = (const int*)d_in[1];
  const int* eattr = (const int*)d_in[2];
  const int* batch = (const int*)d_in[3];
  const float* atom_emb = (const float*)d_in[4];
  const float* bond_emb = (const float*)d_in[5];
  const float* eps = (const float*)d_in[6];
  const float* conv_w1 = (const float*)d_in[7];
  const float* conv_b1 = (const float*)d_in[8];
  const float* conv_bn_g = (const float*)d_in[9];
  const float* conv_bn_b = (const float*)d_in[10];
  const float* conv_w2 = (const float*)d_in[11];
  const float* conv_b2 = (const float*)d_in[12];
  const float* bn_g = (const float*)d_in[13];
  const float* bn_b = (const float*)d_in[14];
  const float* vn_emb = (const float*)d_in[15];
  const float* vn_w1 = (const float*)d_in[16];
  const float* vn_b1 = (const float*)d_in[17];
  const float* vn_bn1_g = (const float*)d_in[18];
  const float* vn_bn1_b = (const float*)d_in[19];
  const float* vn_w2 = (const float*)d_in[20];
  const float* vn_b2 = (const float*)d_in[21];
  const float* vn_bn2_g = (const float*)d_in[22];
  const float* vn_bn2_b = (const float*)d_in[23];
  float* out = (float*)d_out;

  char* w = (char*)d_ws;
  auto alloc = [&](size_t bytes) {
    char* p = w;
    w += (bytes + 255) & ~((size_t)255);
    return p;
  };
  float* h   = (float*)alloc((size_t)NN * D * 4);     // z buffer (mgemm2 out)
  float* hv  = (float*)alloc((size_t)NN * D * 4);
  float* y   = (float*)alloc((size_t)NN * 256 * 4);
  unsigned* Ahi = (unsigned*)alloc((size_t)NN * 64 * 4);  // A' bf16 hi plane
  unsigned* Alo = (unsigned*)alloc((size_t)NN * 64 * 4);  // A' bf16 lo plane
  float* vn  = (float*)alloc((size_t)NG * D * 4);
  float* vt  = (float*)alloc((size_t)NG * D * 4);
  float* yv  = (float*)alloc((size_t)NG * 256 * 4);
  float* zv  = (float*)alloc((size_t)NG * D * 4);
  float* stats = (float*)alloc(16 * 512 * 4);  // slots of (sum[256],sq[256])
  auto SUM = [&](int slot) { return stats + slot * 512; };
  auto SQ  = [&](int slot) { return stats + slot * 512 + 256; };
  const int gx = (NN + 127) / 128;  // 391
  const int gv = (NG + 127) / 128;  // 4
  float* partA = (float*)alloc((size_t)gx * 512 * 4);
  float* partB = (float*)alloc((size_t)gx * 256 * 4);
  int* cnt = (int*)alloc((size_t)NN * 4);
  int* rowptr = (int*)alloc((size_t)(NN + 1) * 4);
  int* cursor = (int*)alloc((size_t)NN * 4);
  unsigned* csr = (unsigned*)alloc((size_t)NE * 4);
  int* bsum = (int*)alloc(128 * 4);
  ushort* wt1h = (ushort*)alloc((size_t)NL * 256 * 128 * 2);
  ushort* wt1l = (ushort*)alloc((size_t)NL * 256 * 128 * 2);
  ushort* wt2h = (ushort*)alloc((size_t)NL * 128 * 256 * 2);
  ushort* wt2l = (ushort*)alloc((size_t)NL * 128 * 256 * 2);
  ushort* vw1h = (ushort*)alloc((size_t)2 * 256 * 128 * 2);
  ushort* vw1l = (ushort*)alloc((size_t)2 * 256 * 128 * 2);
  ushort* vw2h = (ushort*)alloc((size_t)2 * 128 * 256 * 2);
  ushort* vw2l = (ushort*)alloc((size_t)2 * 128 * 256 * 2);

  // zero the atomic stat slots (vn path only)
  hipMemsetAsync(stats, 0, 16 * 512 * 4, stream);

  // weight transpose + split
  k_cvtw<<<dim3(128, NL), 256, 0, stream>>>(conv_w1, 128, 8, wt1h, wt1l);
  k_cvtw<<<dim3(128, NL), 256, 0, stream>>>(conv_w2, 256, 7, wt2h, wt2l);
  k_cvtw<<<dim3(128, 2), 256, 0, stream>>>(vn_w1, 128, 8, vw1h, vw1l);
  k_cvtw<<<dim3(128, 2), 256, 0, stream>>>(vn_w2, 256, 7, vw2h, vw2l);

  // encoders (vn broadcast fused into atom encoder) + vn buffer init
  k_atom<<<(NN * 32 + 255) / 256, 256, 0, stream>>>(x, atom_emb, vn_emb, hv);
  k_vninit<<<(NG * 32 + 255) / 256, 256, 0, stream>>>(vn_emb, vn);

  // CSR build (reused by all 3 layers)
  hipMemsetAsync(cnt, 0, (size_t)NN * 4, stream);
  k_hist<<<(NE + 255) / 256, 256, 0, stream>>>(ei, cnt);
  k_scan_a<<<NBLK, SCAN_B, 0, stream>>>(cnt, rowptr, bsum);
  k_scan_b<<<1, 64, 0, stream>>>(bsum, NBLK);
  k_scan_c<<<NBLK, SCAN_B, 0, stream>>>(rowptr, bsum);
  hipMemcpyAsync(cursor, rowptr, (size_t)NN * 4, hipMemcpyDeviceToDevice, stream);
  k_fill<<<(NE + 255) / 256, 256, 0, stream>>>(ei, eattr, cursor, csr);

  for (int l = 0; l < NL; ++l) {
    const int sc1 = l, sc2 = 3 + l, sv1 = 6 + l, sv2 = 8 + l;
    k_agg<<<(NN * 64 + 255) / 256, 256, 0, stream>>>(
        hv, csr, rowptr, bond_emb + (size_t)l * 3 * 8 * D, eps + l, Ahi, Alo);

    k_mgemm<3, 256, 512, false><<<gx, 512, 0, stream>>>(
        NN, 128, nullptr, (const ushort*)Ahi, (const ushort*)Alo,
        nullptr, nullptr, nullptr, nullptr, 0.f,
        wt1h + (size_t)l * 256 * 128, wt1l + (size_t)l * 256 * 128,
        conv_b1 + l * 256, y, nullptr, nullptr, partA);
    k_red<<<2, 256, 0, stream>>>(partA, gx, 256, SUM(sc1), SQ(sc1));
    k_mgemm<2, 128, 256, false><<<gx, 256, 0, stream>>>(
        NN, 256, y, nullptr, nullptr, SUM(sc1), SQ(sc1),
        conv_bn_g + l * 256, conv_bn_b + l * 256, 1.f / NN,
        wt2h + (size_t)l * 128 * 256, wt2l + (size_t)l * 128 * 256,
        conv_b2 + l * 128, h, nullptr, nullptr, partB);
    k_red<<<1, 256, 0, stream>>>(partB, gx, 128, SUM(sc2), SQ(sc2));

    if (l < NL - 1) {
      k_pool<<<NG, 256, 0, stream>>>(hv, batch, vn, vt);
      k_mgemm<0, 256, 512, true><<<gv, 512, 0, stream>>>(
          NG, 128, vt, nullptr, nullptr, nullptr, nullptr, nullptr, nullptr, 0.f,
          vw1h + (size_t)l * 256 * 128, vw1l + (size_t)l * 256 * 128,
          vn_b1 + l * 256, yv, SUM(sv1), SQ(sv1), nullptr);
      k_mgemm<2, 128, 256, true><<<gv, 256, 0, stream>>>(
          NG, 256, yv, nullptr, nullptr, SUM(sv1), SQ(sv1),
          vn_bn1_g + l * 256, vn_bn1_b + l * 256, 1.f / NG,
          vw2h + (size_t)l * 128 * 256, vw2l + (size_t)l * 128 * 256,
          vn_b2 + l * 128, zv, SUM(sv2), SQ(sv2), nullptr);
      // vn = relu(bn2(zv))
      k_post<<<(NG * 32 + 255) / 256, 256, 0, stream>>>(
          zv, SUM(sv2), SQ(sv2), vn_bn2_g + l * 128, vn_bn2_b + l * 128,
          1.f / NG, nullptr, nullptr, vn, NG, 1);
      // hv_next = relu(bn(z)) + vn_new[batch]
      k_post<<<(NN * 32 + 255) / 256, 256, 0, stream>>>(
          h, SUM(sc2), SQ(sc2), bn_g + l * 128, bn_b + l * 128,
          1.f / NN, vn, batch, hv, NN, 1);
    } else {
      // final output: bn(z), no relu
      k_post<<<(NN * 32 + 255) / 256, 256, 0, stream>>>(
          h, SUM(sc2), SQ(sc2), bn_g + l * 128, bn_b + l * 128,
          1.f / NN, nullptr, nullptr, out, NN, 0);
    }
  }
}

// Round 7
// 824.498 us; speedup vs baseline: 1.6704x; 1.6704x over previous
//
#include <hip/hip_runtime.h>

#define DEV __global__ __launch_bounds__(256)

constexpr int NN = 50000;   // nodes
constexpr int NE = 600000;  // edges
constexpr int D  = 128;     // emb dim
constexpr int NG = 500;     // graphs
constexpr int NL = 3;       // layers
constexpr int SCAN_B = 512;
constexpr int NBLK = (NN + SCAN_B - 1) / SCAN_B;  // 98

typedef __attribute__((ext_vector_type(8))) short bf16x8;
typedef __attribute__((ext_vector_type(4))) float f32x4;

__device__ inline ushort f2bf(float f) {
  unsigned u = __builtin_bit_cast(unsigned, f);
  unsigned r = u + 0x7FFFu + ((u >> 16) & 1u);
  return (ushort)(r >> 16);
}
__device__ inline float bf2f(ushort h) {
  unsigned u = ((unsigned)h) << 16;
  return __builtin_bit_cast(float, u);
}

// ---------------- encoders / elementwise ----------------

// hv0[n][d] = sum_i atom_emb[i][x[n][i]][d] + vn_emb[d]
DEV void k_atom(const int* __restrict__ x, const float* __restrict__ emb,
                const float* __restrict__ vne, float* __restrict__ hv) {
  int t = blockIdx.x * 256 + threadIdx.x;
  int n = t >> 5, c = (t & 31) * 4;
  if (n >= NN) return;
  float4 acc = *(const float4*)(vne + c);
  #pragma unroll
  for (int i = 0; i < 9; ++i) {
    int v = x[n * 9 + i];
    float4 e = *(const float4*)(emb + ((size_t)(i * 128 + v)) * D + c);
    acc.x += e.x; acc.y += e.y; acc.z += e.z; acc.w += e.w;
  }
  *(float4*)(hv + (size_t)n * D + c) = acc;
}

DEV void k_vninit(const float* __restrict__ src, float* __restrict__ vn) {
  int t = blockIdx.x * 256 + threadIdx.x;
  int g = t >> 5, c = (t & 31) * 4;
  if (g >= NG) return;
  *(float4*)(vn + (size_t)g * D + c) = *(const float4*)(src + c);
}

// dst = bn(z) [+relu] [+ vnadd[batch]]   (stats computed inline from sum/sq)
DEV void k_post(const float* __restrict__ z, const float* __restrict__ sum,
                const float* __restrict__ sq, const float* __restrict__ gam,
                const float* __restrict__ bet, float invM,
                const float* __restrict__ vnadd, const int* __restrict__ batch,
                float* __restrict__ dst, int M, int relu) {
  int t = blockIdx.x * 256 + threadIdx.x;
  int n = t >> 5, c = (t & 31) * 4;
  if (n >= M) return;
  f32x4 s = *(const f32x4*)(sum + c);
  f32x4 q = *(const f32x4*)(sq + c);
  f32x4 g = *(const f32x4*)(gam + c);
  f32x4 b = *(const f32x4*)(bet + c);
  f32x4 v = *(const f32x4*)(z + (size_t)n * 128 + c);
  f32x4 o;
  #pragma unroll
  for (int j = 0; j < 4; ++j) {
    float mu = s[j] * invM;
    float var = q[j] * invM - mu * mu;
    float sc = g[j] * rsqrtf(var + 1e-5f);
    float sh = b[j] - mu * sc;
    o[j] = fmaf(v[j], sc, sh);
    if (relu) o[j] = fmaxf(o[j], 0.f);
  }
  if (vnadd) {
    f32x4 a = *(const f32x4*)(vnadd + (size_t)batch[n] * 128 + c);
    #pragma unroll
    for (int j = 0; j < 4; ++j) o[j] += a[j];
  }
  *(f32x4*)(dst + (size_t)n * 128 + c) = o;
}

// ---------------- CSR build ----------------

DEV void k_hist(const int* __restrict__ ei, int* __restrict__ cnt) {
  int e = blockIdx.x * 256 + threadIdx.x;
  if (e < NE) atomicAdd(&cnt[ei[NE + e]], 1);
}

__global__ __launch_bounds__(SCAN_B) void k_scan_a(const int* __restrict__ cnt,
                                                   int* __restrict__ rowptr,
                                                   int* __restrict__ bsum) {
  __shared__ int sh[SCAN_B];
  int i = blockIdx.x * SCAN_B + threadIdx.x;
  int v = (i < NN) ? cnt[i] : 0;
  sh[threadIdx.x] = v;
  __syncthreads();
  for (int off = 1; off < SCAN_B; off <<= 1) {
    int u = (threadIdx.x >= (unsigned)off) ? sh[threadIdx.x - off] : 0;
    __syncthreads();
    sh[threadIdx.x] += u;
    __syncthreads();
  }
  if (i < NN) rowptr[i + 1] = sh[threadIdx.x];
  if (threadIdx.x == SCAN_B - 1) bsum[blockIdx.x] = sh[SCAN_B - 1];
}

__global__ void k_scan_b(int* __restrict__ bsum, int nb) {
  if (threadIdx.x == 0 && blockIdx.x == 0) {
    int acc = 0;
    for (int i = 0; i < nb; ++i) { int v = bsum[i]; bsum[i] = acc; acc += v; }
  }
}

__global__ __launch_bounds__(SCAN_B) void k_scan_c(int* __restrict__ rowptr,
                                                   const int* __restrict__ bsum) {
  int i = blockIdx.x * SCAN_B + threadIdx.x;
  if (i < NN) rowptr[i + 1] += bsum[blockIdx.x];
  if (i == 0) rowptr[0] = 0;
}

DEV void k_fill(const int* __restrict__ ei, const int* __restrict__ eattr,
                int* __restrict__ cursor, unsigned* __restrict__ csr) {
  int e = blockIdx.x * 256 + threadIdx.x;
  if (e >= NE) return;
  int dn = ei[NE + e];
  int p = atomicAdd(&cursor[dn], 1);
  unsigned a0 = (unsigned)eattr[e * 3 + 0];
  unsigned a1 = (unsigned)eattr[e * 3 + 1];
  unsigned a2 = (unsigned)eattr[e * 3 + 2];
  csr[p] = (unsigned)ei[e] | (a0 << 17) | (a1 << 20) | (a2 << 23);
}

// ---- edge aggregation (wave per node) + fused A' = (1+eps)*hv + agg,
//      written pre-split as bf16 hi/lo planes ready for MFMA staging ----

DEV void k_agg(const float* __restrict__ hv, const unsigned* __restrict__ csr,
               const int* __restrict__ rowptr, const float* __restrict__ bond,
               const float* __restrict__ epsp, unsigned* __restrict__ Ahi,
               unsigned* __restrict__ Alo) {
  __shared__ float eb[3 * 8 * D];
  for (int i = threadIdx.x; i < 3 * 8 * D; i += 256) eb[i] = bond[i];
  __syncthreads();
  int wid = (blockIdx.x * 256 + threadIdx.x) >> 6;
  int lane = threadIdx.x & 63;
  if (wid >= NN) return;
  int d0 = lane * 2;
  float ax = 0.f, ay = 0.f;
  int p = rowptr[wid];
  const int p1 = rowptr[wid + 1];
  for (; p + 4 <= p1; p += 4) {
    unsigned pk[4];
    #pragma unroll
    for (int j = 0; j < 4; ++j) pk[j] = csr[p + j];
    float2 hvv[4];
    #pragma unroll
    for (int j = 0; j < 4; ++j)
      hvv[j] = *(const float2*)(hv + (size_t)(pk[j] & 0x1FFFF) * D + d0);
    #pragma unroll
    for (int j = 0; j < 4; ++j) {
      float2 e0 = *(const float2*)(eb + (((pk[j] >> 17) & 7u)) * D + d0);
      float2 e1 = *(const float2*)(eb + (8 + ((pk[j] >> 20) & 7u)) * D + d0);
      float2 e2 = *(const float2*)(eb + (16 + ((pk[j] >> 23) & 7u)) * D + d0);
      ax += fmaxf(hvv[j].x + e0.x + e1.x + e2.x, 0.f);
      ay += fmaxf(hvv[j].y + e0.y + e1.y + e2.y, 0.f);
    }
  }
  for (; p < p1; ++p) {
    unsigned pk = csr[p];
    float2 hvv = *(const float2*)(hv + (size_t)(pk & 0x1FFFF) * D + d0);
    float2 e0 = *(const float2*)(eb + (((pk >> 17) & 7u)) * D + d0);
    float2 e1 = *(const float2*)(eb + (8 + ((pk >> 20) & 7u)) * D + d0);
    float2 e2 = *(const float2*)(eb + (16 + ((pk >> 23) & 7u)) * D + d0);
    ax += fmaxf(hvv.x + e0.x + e1.x + e2.x, 0.f);
    ay += fmaxf(hvv.y + e0.y + e1.y + e2.y, 0.f);
  }
  // fused mgemm1 prologue: A' = (1+eps)*hv + agg, split exact bf16 hi/lo
  float2 hvo = *(const float2*)(hv + (size_t)wid * D + d0);
  float ef = 1.f + epsp[0];
  float a0 = fmaf(ef, hvo.x, ax);
  float a1 = fmaf(ef, hvo.y, ay);
  ushort h0 = f2bf(a0), h1 = f2bf(a1);
  ushort l0 = f2bf(a0 - bf2f(h0)), l1 = f2bf(a1 - bf2f(h1));
  Ahi[(size_t)wid * 64 + lane] = (unsigned)h0 | ((unsigned)h1 << 16);
  Alo[(size_t)wid * 64 + lane] = (unsigned)l0 | ((unsigned)l1 << 16);
}

// ---------------- weight transpose + bf16 hi/lo split ----------------
// src fp32 [L][K][NC] -> th/tl bf16 [L][NC][K]
__global__ __launch_bounds__(256) void k_cvtw(const float* __restrict__ src, int K,
                                              int lognc, ushort* __restrict__ th,
                                              ushort* __restrict__ tl) {
  int NC = 1 << lognc;
  size_t base = (size_t)blockIdx.y * K * NC;
  int i = blockIdx.x * 256 + threadIdx.x;
  if (i >= K * NC) return;
  int k = i >> lognc, c = i & (NC - 1);
  float v = src[base + i];
  ushort hi = f2bf(v);
  th[base + (size_t)c * K + k] = hi;
  tl[base + (size_t)c * K + k] = f2bf(v - bf2f(hi));
}

// ---------------- MFMA bf16x3 GEMM + BN-stats epilogue ----------------
// Y[M x COLS] = A' @ Wt^T + bias
//   AMODE 0: A' = A0 (fp32, split on the fly)
//   AMODE 2: A' = relu(A0 * bnscale[k] + bnshift[k])  (scale/shift from sum/sq)
//   AMODE 3: A' pre-split bf16 planes Ath/Atl (pure copy staging)
// Stats: ATOMIC -> atomicAdd into colsum/colsq; else per-block partials.
template <int AMODE, int COLS, int NT, bool ATOMIC>
__global__ __launch_bounds__(NT) void k_mgemm(
    int M, int K, const float* __restrict__ A0, const ushort* __restrict__ Ath,
    const ushort* __restrict__ Atl, const float* __restrict__ bnsum,
    const float* __restrict__ bnsq, const float* __restrict__ bngam,
    const float* __restrict__ bnbet, float invPrevM,
    const ushort* __restrict__ Wth, const ushort* __restrict__ Wtl,
    const float* __restrict__ bias, float* __restrict__ Y,
    float* __restrict__ colsum, float* __restrict__ colsq,
    float* __restrict__ partial) {
  constexpr int NWC = COLS / 64;
  __shared__ __align__(16) ushort Ah[4][128][8];
  __shared__ __align__(16) ushort Al[4][128][8];
  __shared__ __align__(16) ushort Bh[4][COLS][8];
  __shared__ __align__(16) ushort Bl[4][COLS][8];
  __shared__ float bnsc[AMODE == 2 ? 256 : 1];
  __shared__ float bnsh[AMODE == 2 ? 256 : 1];
  const int tid = threadIdx.x;
  const int row0 = blockIdx.x * 128;
  const int lane = tid & 63, w = tid >> 6;
  const int wr = w / NWC, wc = w % NWC;
  const int kc = lane >> 4, lr = lane & 15;

  if (AMODE == 2) {
    for (int c = tid; c < K; c += NT) {
      float mu = bnsum[c] * invPrevM;
      float var = bnsq[c] * invPrevM - mu * mu;
      float sc = bngam[c] * rsqrtf(var + 1e-5f);
      bnsc[c] = sc;
      bnsh[c] = bnbet[c] - mu * sc;
    }
    __syncthreads();
  }

  f32x4 acc[4][4] = {};

  for (int k0 = 0; k0 < K; k0 += 32) {
    // ---- stage A' ----
    for (int i = tid; i < 512; i += NT) {
      const int c = i >> 7, r = i & 127;
      const int gk = k0 + c * 8;
      const int gr = row0 + r;
      if (AMODE == 3) {
        uint4 vh = make_uint4(0, 0, 0, 0), vl = make_uint4(0, 0, 0, 0);
        if (gr < M) {
          vh = *(const uint4*)(Ath + (size_t)gr * K + gk);
          vl = *(const uint4*)(Atl + (size_t)gr * K + gk);
        }
        *(uint4*)&Ah[c][r][0] = vh;
        *(uint4*)&Al[c][r][0] = vl;
      } else {
        float v[8];
        if (gr < M) {
          f32x4 a0 = *(const f32x4*)(A0 + (size_t)gr * K + gk);
          f32x4 a1 = *(const f32x4*)(A0 + (size_t)gr * K + gk + 4);
          if (AMODE == 2) {
            f32x4 s0 = *(const f32x4*)&bnsc[gk];
            f32x4 s1 = *(const f32x4*)&bnsc[gk + 4];
            f32x4 t0 = *(const f32x4*)&bnsh[gk];
            f32x4 t1 = *(const f32x4*)&bnsh[gk + 4];
            #pragma unroll
            for (int j = 0; j < 4; ++j) {
              v[j] = fmaxf(fmaf(a0[j], s0[j], t0[j]), 0.f);
              v[4 + j] = fmaxf(fmaf(a1[j], s1[j], t1[j]), 0.f);
            }
          } else {
            #pragma unroll
            for (int j = 0; j < 4; ++j) { v[j] = a0[j]; v[4 + j] = a1[j]; }
          }
        } else {
          #pragma unroll
          for (int j = 0; j < 8; ++j) v[j] = 0.f;
        }
        alignas(16) ushort th[8], tl[8];
        #pragma unroll
        for (int j = 0; j < 8; ++j) {
          ushort hi = f2bf(v[j]);
          th[j] = hi;
          tl[j] = f2bf(v[j] - bf2f(hi));
        }
        *(uint4*)&Ah[c][r][0] = *(const uint4*)th;
        *(uint4*)&Al[c][r][0] = *(const uint4*)tl;
      }
    }
    // ---- stage B ----
    for (int i = tid; i < COLS * 4; i += NT) {
      const int c = i / COLS, r = i % COLS;
      const int gk = k0 + c * 8;
      *(uint4*)&Bh[c][r][0] = *(const uint4*)(Wth + (size_t)r * K + gk);
      *(uint4*)&Bl[c][r][0] = *(const uint4*)(Wtl + (size_t)r * K + gk);
    }
    __syncthreads();
    // ---- MFMA: 3-term bf16 emulation of fp32 ----
    bf16x8 bhf[4], blf[4];
    #pragma unroll
    for (int fc = 0; fc < 4; ++fc) {
      bhf[fc] = *(const bf16x8*)&Bh[kc][wc * 64 + fc * 16 + lr][0];
      blf[fc] = *(const bf16x8*)&Bl[kc][wc * 64 + fc * 16 + lr][0];
    }
    #pragma unroll
    for (int fr = 0; fr < 4; ++fr) {
      bf16x8 ahf = *(const bf16x8*)&Ah[kc][wr * 64 + fr * 16 + lr][0];
      bf16x8 alf = *(const bf16x8*)&Al[kc][wr * 64 + fr * 16 + lr][0];
      #pragma unroll
      for (int fc = 0; fc < 4; ++fc) {
        acc[fr][fc] = __builtin_amdgcn_mfma_f32_16x16x32_bf16(ahf, bhf[fc], acc[fr][fc], 0, 0, 0);
        acc[fr][fc] = __builtin_amdgcn_mfma_f32_16x16x32_bf16(alf, bhf[fc], acc[fr][fc], 0, 0, 0);
        acc[fr][fc] = __builtin_amdgcn_mfma_f32_16x16x32_bf16(ahf, blf[fc], acc[fr][fc], 0, 0, 0);
      }
    }
    __syncthreads();
  }

  // ---- epilogue: bias, store, block-level column stats (no global atomics) ----
  float* sred = reinterpret_cast<float*>(&Ah[0][0][0]);  // [2][COLS] (Ah is dead)
  float* qred = sred + 2 * COLS;
  #pragma unroll
  for (int fc = 0; fc < 4; ++fc) {
    const int gc = wc * 64 + fc * 16 + lr;
    const float bb = bias[gc];
    float cs = 0.f, cq = 0.f;
    #pragma unroll
    for (int fr = 0; fr < 4; ++fr) {
      const int rb = row0 + wr * 64 + fr * 16 + kc * 4;
      #pragma unroll
      for (int rg = 0; rg < 4; ++rg) {
        int gr = rb + rg;
        if (gr < M) {
          float v = acc[fr][fc][rg] + bb;
          Y[(size_t)gr * COLS + gc] = v;
          cs += v;
          cq += v * v;
        }
      }
    }
    cs += __shfl_xor(cs, 16); cs += __shfl_xor(cs, 32);
    cq += __shfl_xor(cq, 16); cq += __shfl_xor(cq, 32);
    if (kc == 0) {
      sred[wr * COLS + gc] = cs;
      qred[wr * COLS + gc] = cq;
    }
  }
  __syncthreads();
  for (int c = tid; c < COLS; c += NT) {
    float s = sred[c] + sred[COLS + c];
    float q = qred[c] + qred[COLS + c];
    if (ATOMIC) {
      atomicAdd(&colsum[c], s);
      atomicAdd(&colsq[c], q);
    } else {
      partial[(size_t)blockIdx.x * 2 * COLS + c] = s;
      partial[(size_t)blockIdx.x * 2 * COLS + COLS + c] = q;
    }
  }
}

// sum partials over blocks -> SUM/SQ.  One block per output element j in
// [0, 2*width); 256 threads stride over nb partials, wave+LDS reduce.
__global__ __launch_bounds__(256) void k_red(const float* __restrict__ part, int nb,
                                             int width, float* __restrict__ outSum,
                                             float* __restrict__ outSq) {
  const int j = blockIdx.x;  // 0 .. 2*width-1
  float a = 0.f;
  for (int b = threadIdx.x; b < nb; b += 256)
    a += part[(size_t)b * 2 * width + j];
  a += __shfl_xor(a, 1);  a += __shfl_xor(a, 2);  a += __shfl_xor(a, 4);
  a += __shfl_xor(a, 8);  a += __shfl_xor(a, 16); a += __shfl_xor(a, 32);
  __shared__ float red[4];
  const int lane = threadIdx.x & 63, wv = threadIdx.x >> 6;
  if (lane == 0) red[wv] = a;
  __syncthreads();
  if (threadIdx.x == 0) {
    float s = red[0] + red[1] + red[2] + red[3];
    if (j < width) outSum[j] = s;
    else outSq[j - width] = s;
  }
}

// ---------------- graph pooling ----------------

DEV void k_pool(const float* __restrict__ hv, const int* __restrict__ batch,
                const float* __restrict__ vn, float* __restrict__ vt) {
  int g = blockIdx.x;
  int lo = 0, hi = NN;
  while (lo < hi) { int mid = (lo + hi) >> 1; if (batch[mid] < g) lo = mid + 1; else hi = mid; }
  int s = lo;
  hi = NN;
  while (lo < hi) { int mid = (lo + hi) >> 1; if (batch[mid] < g + 1) lo = mid + 1; else hi = mid; }
  int e = lo;
  int ry = threadIdx.x >> 5, cx = threadIdx.x & 31;
  float4 acc = make_float4(0.f, 0.f, 0.f, 0.f);
  for (int n = s + ry; n < e; n += 8) {
    float4 v = *(const float4*)(hv + (size_t)n * D + cx * 4);
    acc.x += v.x; acc.y += v.y; acc.z += v.z; acc.w += v.w;
  }
  __shared__ float4 red[8][32];
  red[ry][cx] = acc;
  __syncthreads();
  for (int st = 4; st >= 1; st >>= 1) {
    if (ry < st) {
      float4 o = red[ry + st][cx];
      red[ry][cx].x += o.x; red[ry][cx].y += o.y;
      red[ry][cx].z += o.z; red[ry][cx].w += o.w;
    }
    __syncthreads();
  }
  if (ry == 0) {
    float4 v = red[0][cx];
    float4 b = *(const float4*)(vn + (size_t)g * D + cx * 4);
    v.x += b.x; v.y += b.y; v.z += b.z; v.w += b.w;
    *(float4*)(vt + (size_t)g * D + cx * 4) = v;
  }
}

// ---------------- launcher ----------------

extern "C" void kernel_launch(void* const* d_in, const int* in_sizes, int n_in,
                              void* d_out, int out_size, void* d_ws, size_t ws_size,
                              hipStream_t stream) {
  const int* x = (const int*)d_in[0];
  const int* ei = (const int*)d_in[1];
  const int* eattr = (const int*)d_in[2];
  const int* batch = (const int*)d_in[3];
  const float* atom_emb = (const float*)d_in[4];
  const float* bond_emb = (const float*)d_in[5];
  const float* eps = (const float*)d_in[6];
  const float* conv_w1 = (const float*)d_in[7];
  const float* conv_b1 = (const float*)d_in[8];
  const float* conv_bn_g = (const float*)d_in[9];
  const float* conv_bn_b = (const float*)d_in[10];
  const float* conv_w2 = (const float*)d_in[11];
  const float* conv_b2 = (const float*)d_in[12];
  const float* bn_g = (const float*)d_in[13];
  const float* bn_b = (const float*)d_in[14];
  const float* vn_emb = (const float*)d_in[15];
  const float* vn_w1 = (const float*)d_in[16];
  const float* vn_b1 = (const float*)d_in[17];
  const float* vn_bn1_g = (const float*)d_in[18];
  const float* vn_bn1_b = (const float*)d_in[19];
  const float* vn_w2 = (const float*)d_in[20];
  const float* vn_b2 = (const float*)d_in[21];
  const float* vn_bn2_g = (const float*)d_in[22];
  const float* vn_bn2_b = (const float*)d_in[23];
  float* out = (float*)d_out;

  char* w = (char*)d_ws;
  auto alloc = [&](size_t bytes) {
    char* p = w;
    w += (bytes + 255) & ~((size_t)255);
    return p;
  };
  float* h   = (float*)alloc((size_t)NN * D * 4);     // z buffer (mgemm2 out)
  float* hv  = (float*)alloc((size_t)NN * D * 4);
  float* y   = (float*)alloc((size_t)NN * 256 * 4);
  unsigned* Ahi = (unsigned*)alloc((size_t)NN * 64 * 4);  // A' bf16 hi plane
  unsigned* Alo = (unsigned*)alloc((size_t)NN * 64 * 4);  // A' bf16 lo plane
  float* vn  = (float*)alloc((size_t)NG * D * 4);
  float* vt  = (float*)alloc((size_t)NG * D * 4);
  float* yv  = (float*)alloc((size_t)NG * 256 * 4);
  float* zv  = (float*)alloc((size_t)NG * D * 4);
  float* stats = (float*)alloc(16 * 512 * 4);  // slots of (sum[256],sq[256])
  auto SUM = [&](int slot) { return stats + slot * 512; };
  auto SQ  = [&](int slot) { return stats + slot * 512 + 256; };
  const int gx = (NN + 127) / 128;  // 391
  const int gv = (NG + 127) / 128;  // 4
  float* partA = (float*)alloc((size_t)gx * 512 * 4);
  float* partB = (float*)alloc((size_t)gx * 256 * 4);
  int* cnt = (int*)alloc((size_t)NN * 4);
  int* rowptr = (int*)alloc((size_t)(NN + 1) * 4);
  int* cursor = (int*)alloc((size_t)NN * 4);
  unsigned* csr = (unsigned*)alloc((size_t)NE * 4);
  int* bsum = (int*)alloc(128 * 4);
  ushort* wt1h = (ushort*)alloc((size_t)NL * 256 * 128 * 2);
  ushort* wt1l = (ushort*)alloc((size_t)NL * 256 * 128 * 2);
  ushort* wt2h = (ushort*)alloc((size_t)NL * 128 * 256 * 2);
  ushort* wt2l = (ushort*)alloc((size_t)NL * 128 * 256 * 2);
  ushort* vw1h = (ushort*)alloc((size_t)2 * 256 * 128 * 2);
  ushort* vw1l = (ushort*)alloc((size_t)2 * 256 * 128 * 2);
  ushort* vw2h = (ushort*)alloc((size_t)2 * 128 * 256 * 2);
  ushort* vw2l = (ushort*)alloc((size_t)2 * 128 * 256 * 2);

  // zero the atomic stat slots (vn path only)
  hipMemsetAsync(stats, 0, 16 * 512 * 4, stream);

  // weight transpose + split
  k_cvtw<<<dim3(128, NL), 256, 0, stream>>>(conv_w1, 128, 8, wt1h, wt1l);
  k_cvtw<<<dim3(128, NL), 256, 0, stream>>>(conv_w2, 256, 7, wt2h, wt2l);
  k_cvtw<<<dim3(128, 2), 256, 0, stream>>>(vn_w1, 128, 8, vw1h, vw1l);
  k_cvtw<<<dim3(128, 2), 256, 0, stream>>>(vn_w2, 256, 7, vw2h, vw2l);

  // encoders (vn broadcast fused into atom encoder) + vn buffer init
  k_atom<<<(NN * 32 + 255) / 256, 256, 0, stream>>>(x, atom_emb, vn_emb, hv);
  k_vninit<<<(NG * 32 + 255) / 256, 256, 0, stream>>>(vn_emb, vn);

  // CSR build (reused by all 3 layers)
  hipMemsetAsync(cnt, 0, (size_t)NN * 4, stream);
  k_hist<<<(NE + 255) / 256, 256, 0, stream>>>(ei, cnt);
  k_scan_a<<<NBLK, SCAN_B, 0, stream>>>(cnt, rowptr, bsum);
  k_scan_b<<<1, 64, 0, stream>>>(bsum, NBLK);
  k_scan_c<<<NBLK, SCAN_B, 0, stream>>>(rowptr, bsum);
  hipMemcpyAsync(cursor, rowptr, (size_t)NN * 4, hipMemcpyDeviceToDevice, stream);
  k_fill<<<(NE + 255) / 256, 256, 0, stream>>>(ei, eattr, cursor, csr);

  for (int l = 0; l < NL; ++l) {
    const int sc1 = l, sc2 = 3 + l, sv1 = 6 + l, sv2 = 8 + l;
    k_agg<<<(NN * 64 + 255) / 256, 256, 0, stream>>>(
        hv, csr, rowptr, bond_emb + (size_t)l * 3 * 8 * D, eps + l, Ahi, Alo);

    k_mgemm<3, 256, 512, false><<<gx, 512, 0, stream>>>(
        NN, 128, nullptr, (const ushort*)Ahi, (const ushort*)Alo,
        nullptr, nullptr, nullptr, nullptr, 0.f,
        wt1h + (size_t)l * 256 * 128, wt1l + (size_t)l * 256 * 128,
        conv_b1 + l * 256, y, nullptr, nullptr, partA);
    k_red<<<512, 256, 0, stream>>>(partA, gx, 256, SUM(sc1), SQ(sc1));
    k_mgemm<2, 128, 256, false><<<gx, 256, 0, stream>>>(
        NN, 256, y, nullptr, nullptr, SUM(sc1), SQ(sc1),
        conv_bn_g + l * 256, conv_bn_b + l * 256, 1.f / NN,
        wt2h + (size_t)l * 128 * 256, wt2l + (size_t)l * 128 * 256,
        conv_b2 + l * 128, h, nullptr, nullptr, partB);
    k_red<<<256, 256, 0, stream>>>(partB, gx, 128, SUM(sc2), SQ(sc2));

    if (l < NL - 1) {
      k_pool<<<NG, 256, 0, stream>>>(hv, batch, vn, vt);
      k_mgemm<0, 256, 512, true><<<gv, 512, 0, stream>>>(
          NG, 128, vt, nullptr, nullptr, nullptr, nullptr, nullptr, nullptr, 0.f,
          vw1h + (size_t)l * 256 * 128, vw1l + (size_t)l * 256 * 128,
          vn_b1 + l * 256, yv, SUM(sv1), SQ(sv1), nullptr);
      k_mgemm<2, 128, 256, true><<<gv, 256, 0, stream>>>(
          NG, 256, yv, nullptr, nullptr, SUM(sv1), SQ(sv1),
          vn_bn1_g + l * 256, vn_bn1_b + l * 256, 1.f / NG,
          vw2h + (size_t)l * 128 * 256, vw2l + (size_t)l * 128 * 256,
          vn_b2 + l * 128, zv, SUM(sv2), SQ(sv2), nullptr);
      // vn = relu(bn2(zv))
      k_post<<<(NG * 32 + 255) / 256, 256, 0, stream>>>(
          zv, SUM(sv2), SQ(sv2), vn_bn2_g + l * 128, vn_bn2_b + l * 128,
          1.f / NG, nullptr, nullptr, vn, NG, 1);
      // hv_next = relu(bn(z)) + vn_new[batch]
      k_post<<<(NN * 32 + 255) / 256, 256, 0, stream>>>(
          h, SUM(sc2), SQ(sc2), bn_g + l * 128, bn_b + l * 128,
          1.f / NN, vn, batch, hv, NN, 1);
    } else {
      // final output: bn(z), no relu
      k_post<<<(NN * 32 + 255) / 256, 256, 0, stream>>>(
          h, SUM(sc2), SQ(sc2), bn_g + l * 128, bn_b + l * 128,
          1.f / NN, nullptr, nullptr, out, NN, 0);
    }
  }
}

// Round 14
// 793.873 us; speedup vs baseline: 1.7349x; 1.0386x over previous
//
#include <hip/hip_runtime.h>

#define DEV __global__ __launch_bounds__(256)

constexpr int NN = 50000;   // nodes
constexpr int NE = 600000;  // edges
constexpr int D  = 128;     // emb dim
constexpr int NG = 500;     // graphs
constexpr int NL = 3;       // layers
constexpr int SCAN_B = 512;
constexpr int NBLK = (NN + SCAN_B - 1) / SCAN_B;  // 98

typedef __attribute__((ext_vector_type(8))) short bf16x8;
typedef __attribute__((ext_vector_type(4))) float f32x4;

__device__ inline ushort f2bf(float f) {
  unsigned u = __builtin_bit_cast(unsigned, f);
  unsigned r = u + 0x7FFFu + ((u >> 16) & 1u);
  return (ushort)(r >> 16);
}
__device__ inline float bf2f(ushort h) {
  unsigned u = ((unsigned)h) << 16;
  return __builtin_bit_cast(float, u);
}

// ---------------- encoders / elementwise ----------------

// blocks [0, NB_ATOM): hv0[n][d] = sum_i atom_emb[i][x[n][i]][d] + vn_emb[d]
// blocks [NB_ATOM, ..): vn[g] = vn_emb
constexpr int NB_ATOM = (NN * 32 + 255) / 256;  // 6250
constexpr int NB_VNI  = (NG * 32 + 255) / 256;  // 63
DEV void k_atomvn(const int* __restrict__ x, const float* __restrict__ emb,
                  const float* __restrict__ vne, float* __restrict__ hv,
                  float* __restrict__ vn) {
  if ((int)blockIdx.x >= NB_ATOM) {
    int t = (blockIdx.x - NB_ATOM) * 256 + threadIdx.x;
    int g = t >> 5, c = (t & 31) * 4;
    if (g < NG) *(float4*)(vn + (size_t)g * D + c) = *(const float4*)(vne + c);
    return;
  }
  int t = blockIdx.x * 256 + threadIdx.x;
  int n = t >> 5, c = (t & 31) * 4;
  if (n >= NN) return;
  float4 acc = *(const float4*)(vne + c);
  #pragma unroll
  for (int i = 0; i < 9; ++i) {
    int v = x[n * 9 + i];
    float4 e = *(const float4*)(emb + ((size_t)(i * 128 + v)) * D + c);
    acc.x += e.x; acc.y += e.y; acc.z += e.z; acc.w += e.w;
  }
  *(float4*)(hv + (size_t)n * D + c) = acc;
}

// dst = bn(z) [+relu] [+ vnadd[batch]]   (stats computed inline from sum/sq)
DEV void k_post(const float* __restrict__ z, const float* __restrict__ sum,
                const float* __restrict__ sq, const float* __restrict__ gam,
                const float* __restrict__ bet, float invM,
                const float* __restrict__ vnadd, const int* __restrict__ batch,
                float* __restrict__ dst, int M, int relu) {
  int t = blockIdx.x * 256 + threadIdx.x;
  int n = t >> 5, c = (t & 31) * 4;
  if (n >= M) return;
  f32x4 s = *(const f32x4*)(sum + c);
  f32x4 q = *(const f32x4*)(sq + c);
  f32x4 g = *(const f32x4*)(gam + c);
  f32x4 b = *(const f32x4*)(bet + c);
  f32x4 v = *(const f32x4*)(z + (size_t)n * 128 + c);
  f32x4 o;
  #pragma unroll
  for (int j = 0; j < 4; ++j) {
    float mu = s[j] * invM;
    float var = q[j] * invM - mu * mu;
    float sc = g[j] * rsqrtf(var + 1e-5f);
    float sh = b[j] - mu * sc;
    o[j] = fmaf(v[j], sc, sh);
    if (relu) o[j] = fmaxf(o[j], 0.f);
  }
  if (vnadd) {
    f32x4 a = *(const f32x4*)(vnadd + (size_t)batch[n] * 128 + c);
    #pragma unroll
    for (int j = 0; j < 4; ++j) o[j] += a[j];
  }
  *(f32x4*)(dst + (size_t)n * 128 + c) = o;
}

// ---------------- CSR build ----------------

DEV void k_hist(const int* __restrict__ ei, int* __restrict__ cnt) {
  int e = blockIdx.x * 256 + threadIdx.x;
  if (e < NE) atomicAdd(&cnt[ei[NE + e]], 1);
}

__global__ __launch_bounds__(SCAN_B) void k_scan_a(const int* __restrict__ cnt,
                                                   int* __restrict__ rowptr,
                                                   int* __restrict__ bsum) {
  __shared__ int sh[SCAN_B];
  int i = blockIdx.x * SCAN_B + threadIdx.x;
  int v = (i < NN) ? cnt[i] : 0;
  sh[threadIdx.x] = v;
  __syncthreads();
  for (int off = 1; off < SCAN_B; off <<= 1) {
    int u = (threadIdx.x >= (unsigned)off) ? sh[threadIdx.x - off] : 0;
    __syncthreads();
    sh[threadIdx.x] += u;
    __syncthreads();
  }
  if (i < NN) rowptr[i + 1] = sh[threadIdx.x];
  if (threadIdx.x == SCAN_B - 1) bsum[blockIdx.x] = sh[SCAN_B - 1];
}

// adds exclusive prefix of block totals (bsum holds raw block totals)
__global__ __launch_bounds__(SCAN_B) void k_scan_c(int* __restrict__ rowptr,
                                                   const int* __restrict__ bsum) {
  __shared__ int off;
  if (threadIdx.x == 0) {
    int a = 0;
    for (int b = 0; b < (int)blockIdx.x; ++b) a += bsum[b];
    off = a;
  }
  __syncthreads();
  int i = blockIdx.x * SCAN_B + threadIdx.x;
  if (i < NN) rowptr[i + 1] += off;
  if (i == 0) rowptr[0] = 0;
}

DEV void k_fill(const int* __restrict__ ei, const int* __restrict__ eattr,
                int* __restrict__ cursor, unsigned* __restrict__ csr) {
  int e = blockIdx.x * 256 + threadIdx.x;
  if (e >= NE) return;
  int dn = ei[NE + e];
  int p = atomicAdd(&cursor[dn], 1);
  unsigned a0 = (unsigned)eattr[e * 3 + 0];
  unsigned a1 = (unsigned)eattr[e * 3 + 1];
  unsigned a2 = (unsigned)eattr[e * 3 + 2];
  csr[p] = (unsigned)ei[e] | (a0 << 17) | (a1 << 20) | (a2 << 23);
}

// ---- edge aggregation (wave per node) + fused A' = (1+eps)*hv + agg,
//      written pre-split as bf16 hi/lo planes ready for MFMA staging ----

DEV void k_agg(const float* __restrict__ hv, const unsigned* __restrict__ csr,
               const int* __restrict__ rowptr, const float* __restrict__ bond,
               const float* __restrict__ epsp, unsigned* __restrict__ Ahi,
               unsigned* __restrict__ Alo) {
  __shared__ float eb[3 * 8 * D];
  for (int i = threadIdx.x; i < 3 * 8 * D; i += 256) eb[i] = bond[i];
  __syncthreads();
  int wid = (blockIdx.x * 256 + threadIdx.x) >> 6;
  int lane = threadIdx.x & 63;
  if (wid >= NN) return;
  int d0 = lane * 2;
  float ax = 0.f, ay = 0.f;
  int p = rowptr[wid];
  const int p1 = rowptr[wid + 1];
  for (; p + 4 <= p1; p += 4) {
    unsigned pk[4];
    #pragma unroll
    for (int j = 0; j < 4; ++j) pk[j] = csr[p + j];
    float2 hvv[4];
    #pragma unroll
    for (int j = 0; j < 4; ++j)
      hvv[j] = *(const float2*)(hv + (size_t)(pk[j] & 0x1FFFF) * D + d0);
    #pragma unroll
    for (int j = 0; j < 4; ++j) {
      float2 e0 = *(const float2*)(eb + (((pk[j] >> 17) & 7u)) * D + d0);
      float2 e1 = *(const float2*)(eb + (8 + ((pk[j] >> 20) & 7u)) * D + d0);
      float2 e2 = *(const float2*)(eb + (16 + ((pk[j] >> 23) & 7u)) * D + d0);
      ax += fmaxf(hvv[j].x + e0.x + e1.x + e2.x, 0.f);
      ay += fmaxf(hvv[j].y + e0.y + e1.y + e2.y, 0.f);
    }
  }
  for (; p < p1; ++p) {
    unsigned pk = csr[p];
    float2 hvv = *(const float2*)(hv + (size_t)(pk & 0x1FFFF) * D + d0);
    float2 e0 = *(const float2*)(eb + (((pk >> 17) & 7u)) * D + d0);
    float2 e1 = *(const float2*)(eb + (8 + ((pk >> 20) & 7u)) * D + d0);
    float2 e2 = *(const float2*)(eb + (16 + ((pk >> 23) & 7u)) * D + d0);
    ax += fmaxf(hvv.x + e0.x + e1.x + e2.x, 0.f);
    ay += fmaxf(hvv.y + e0.y + e1.y + e2.y, 0.f);
  }
  // fused mgemm1 prologue: A' = (1+eps)*hv + agg, split exact bf16 hi/lo
  float2 hvo = *(const float2*)(hv + (size_t)wid * D + d0);
  float ef = 1.f + epsp[0];
  float a0 = fmaf(ef, hvo.x, ax);
  float a1 = fmaf(ef, hvo.y, ay);
  ushort h0 = f2bf(a0), h1 = f2bf(a1);
  ushort l0 = f2bf(a0 - bf2f(h0)), l1 = f2bf(a1 - bf2f(h1));
  Ahi[(size_t)wid * 64 + lane] = (unsigned)h0 | ((unsigned)h1 << 16);
  Alo[(size_t)wid * 64 + lane] = (unsigned)l0 | ((unsigned)l1 << 16);
}

// ---------------- weight transpose + bf16 hi/lo split (all weights, 1 kernel) ----
// seg 0-2: conv_w1[l], 3-5: conv_w2[l], 6-7: vn_w1[l], 8-9: vn_w2[l]
__global__ __launch_bounds__(256) void k_cvtw_all(
    const float* __restrict__ w1, const float* __restrict__ w2,
    const float* __restrict__ v1, const float* __restrict__ v2,
    ushort* __restrict__ t1h, ushort* __restrict__ t1l,
    ushort* __restrict__ t2h, ushort* __restrict__ t2l,
    ushort* __restrict__ u1h, ushort* __restrict__ u1l,
    ushort* __restrict__ u2h, ushort* __restrict__ u2l) {
  int seg = blockIdx.y;
  const float* src; ushort *th, *tl; int K, lognc, idx;
  if (seg < 3)      { src = w1; th = t1h; tl = t1l; K = 128; lognc = 8; idx = seg; }
  else if (seg < 6) { src = w2; th = t2h; tl = t2l; K = 256; lognc = 7; idx = seg - 3; }
  else if (seg < 8) { src = v1; th = u1h; tl = u1l; K = 128; lognc = 8; idx = seg - 6; }
  else              { src = v2; th = u2h; tl = u2l; K = 256; lognc = 7; idx = seg - 8; }
  size_t base = (size_t)idx * (K << lognc);
  int i = blockIdx.x * 256 + threadIdx.x;
  if (i >= (K << lognc)) return;
  int k = i >> lognc, c = i & ((1 << lognc) - 1);
  float v = src[base + i];
  ushort hi = f2bf(v);
  th[base + (size_t)c * K + k] = hi;
  tl[base + (size_t)c * K + k] = f2bf(v - bf2f(hi));
}

// ---------------- MFMA bf16x3 GEMM + BN-stats epilogue ----------------
// Y[M x COLS] = A' @ Wt^T + bias
//   AMODE 0: A' = A0 (fp32, split on the fly)
//   AMODE 2: A' = relu(bf2f(Abh[..]) * bnscale[k] + bnshift[k])  (bf16 input)
//   AMODE 3: A' pre-split bf16 planes Abh/Abl (pure copy staging)
// Output: OUTBF ? Yb (bf16, round-nearest) : Yf (fp32). Stats from exact fp32.
// Stats: ATOMIC -> atomicAdd into colsum/colsq; else per-block partials.
template <int AMODE, int COLS, int NT, bool ATOMIC, bool OUTBF>
__global__ __launch_bounds__(NT) void k_mgemm(
    int M, int K, const float* __restrict__ A0, const ushort* __restrict__ Abh,
    const ushort* __restrict__ Abl, const float* __restrict__ bnsum,
    const float* __restrict__ bnsq, const float* __restrict__ bngam,
    const float* __restrict__ bnbet, float invPrevM,
    const ushort* __restrict__ Wth, const ushort* __restrict__ Wtl,
    const float* __restrict__ bias, float* __restrict__ Yf,
    ushort* __restrict__ Yb, float* __restrict__ colsum,
    float* __restrict__ colsq, float* __restrict__ partial) {
  constexpr int NWC = COLS / 64;
  __shared__ __align__(16) ushort Ah[4][128][8];
  __shared__ __align__(16) ushort Al[4][128][8];
  __shared__ __align__(16) ushort Bh[4][COLS][8];
  __shared__ __align__(16) ushort Bl[4][COLS][8];
  __shared__ float bnsc[AMODE == 2 ? 256 : 1];
  __shared__ float bnsh[AMODE == 2 ? 256 : 1];
  const int tid = threadIdx.x;
  const int row0 = blockIdx.x * 128;
  const int lane = tid & 63, w = tid >> 6;
  const int wr = w / NWC, wc = w % NWC;
  const int kc = lane >> 4, lr = lane & 15;

  if (AMODE == 2) {
    for (int c = tid; c < K; c += NT) {
      float mu = bnsum[c] * invPrevM;
      float var = bnsq[c] * invPrevM - mu * mu;
      float sc = bngam[c] * rsqrtf(var + 1e-5f);
      bnsc[c] = sc;
      bnsh[c] = bnbet[c] - mu * sc;
    }
    __syncthreads();
  }

  f32x4 acc[4][4] = {};

  for (int k0 = 0; k0 < K; k0 += 32) {
    // ---- stage A' ----
    for (int i = tid; i < 512; i += NT) {
      const int c = i >> 7, r = i & 127;
      const int gk = k0 + c * 8;
      const int gr = row0 + r;
      if (AMODE == 3) {
        uint4 vh = make_uint4(0, 0, 0, 0), vl = make_uint4(0, 0, 0, 0);
        if (gr < M) {
          vh = *(const uint4*)(Abh + (size_t)gr * K + gk);
          vl = *(const uint4*)(Abl + (size_t)gr * K + gk);
        }
        *(uint4*)&Ah[c][r][0] = vh;
        *(uint4*)&Al[c][r][0] = vl;
      } else {
        float v[8];
        if (gr < M) {
          if (AMODE == 2) {
            alignas(16) ushort yq[8];
            *(uint4*)yq = *(const uint4*)(Abh + (size_t)gr * K + gk);
            #pragma unroll
            for (int j = 0; j < 8; ++j)
              v[j] = fmaxf(fmaf(bf2f(yq[j]), bnsc[gk + j], bnsh[gk + j]), 0.f);
          } else {
            f32x4 a0 = *(const f32x4*)(A0 + (size_t)gr * K + gk);
            f32x4 a1 = *(const f32x4*)(A0 + (size_t)gr * K + gk + 4);
            #pragma unroll
            for (int j = 0; j < 4; ++j) { v[j] = a0[j]; v[4 + j] = a1[j]; }
          }
        } else {
          #pragma unroll
          for (int j = 0; j < 8; ++j) v[j] = 0.f;
        }
        alignas(16) ushort th[8], tl[8];
        #pragma unroll
        for (int j = 0; j < 8; ++j) {
          ushort hi = f2bf(v[j]);
          th[j] = hi;
          tl[j] = f2bf(v[j] - bf2f(hi));
        }
        *(uint4*)&Ah[c][r][0] = *(const uint4*)th;
        *(uint4*)&Al[c][r][0] = *(const uint4*)tl;
      }
    }
    // ---- stage B ----
    for (int i = tid; i < COLS * 4; i += NT) {
      const int c = i / COLS, r = i % COLS;
      const int gk = k0 + c * 8;
      *(uint4*)&Bh[c][r][0] = *(const uint4*)(Wth + (size_t)r * K + gk);
      *(uint4*)&Bl[c][r][0] = *(const uint4*)(Wtl + (size_t)r * K + gk);
    }
    __syncthreads();
    // ---- MFMA: 3-term bf16 emulation of fp32 ----
    bf16x8 bhf[4], blf[4];
    #pragma unroll
    for (int fc = 0; fc < 4; ++fc) {
      bhf[fc] = *(const bf16x8*)&Bh[kc][wc * 64 + fc * 16 + lr][0];
      blf[fc] = *(const bf16x8*)&Bl[kc][wc * 64 + fc * 16 + lr][0];
    }
    #pragma unroll
    for (int fr = 0; fr < 4; ++fr) {
      bf16x8 ahf = *(const bf16x8*)&Ah[kc][wr * 64 + fr * 16 + lr][0];
      bf16x8 alf = *(const bf16x8*)&Al[kc][wr * 64 + fr * 16 + lr][0];
      #pragma unroll
      for (int fc = 0; fc < 4; ++fc) {
        acc[fr][fc] = __builtin_amdgcn_mfma_f32_16x16x32_bf16(ahf, bhf[fc], acc[fr][fc], 0, 0, 0);
        acc[fr][fc] = __builtin_amdgcn_mfma_f32_16x16x32_bf16(alf, bhf[fc], acc[fr][fc], 0, 0, 0);
        acc[fr][fc] = __builtin_amdgcn_mfma_f32_16x16x32_bf16(ahf, blf[fc], acc[fr][fc], 0, 0, 0);
      }
    }
    __syncthreads();
  }

  // ---- epilogue: bias, store, block-level column stats (no global atomics) ----
  float* sred = reinterpret_cast<float*>(&Ah[0][0][0]);  // [2][COLS] (Ah is dead)
  float* qred = sred + 2 * COLS;
  #pragma unroll
  for (int fc = 0; fc < 4; ++fc) {
    const int gc = wc * 64 + fc * 16 + lr;
    const float bb = bias[gc];
    float cs = 0.f, cq = 0.f;
    #pragma unroll
    for (int fr = 0; fr < 4; ++fr) {
      const int rb = row0 + wr * 64 + fr * 16 + kc * 4;
      #pragma unroll
      for (int rg = 0; rg < 4; ++rg) {
        int gr = rb + rg;
        if (gr < M) {
          float v = acc[fr][fc][rg] + bb;
          if (OUTBF) Yb[(size_t)gr * COLS + gc] = f2bf(v);
          else       Yf[(size_t)gr * COLS + gc] = v;
          cs += v;
          cq += v * v;
        }
      }
    }
    cs += __shfl_xor(cs, 16); cs += __shfl_xor(cs, 32);
    cq += __shfl_xor(cq, 16); cq += __shfl_xor(cq, 32);
    if (kc == 0) {
      sred[wr * COLS + gc] = cs;
      qred[wr * COLS + gc] = cq;
    }
  }
  __syncthreads();
  for (int c = tid; c < COLS; c += NT) {
    float s = sred[c] + sred[COLS + c];
    float q = qred[c] + qred[COLS + c];
    if (ATOMIC) {
      atomicAdd(&colsum[c], s);
      atomicAdd(&colsq[c], q);
    } else {
      partial[(size_t)blockIdx.x * 2 * COLS + c] = s;
      partial[(size_t)blockIdx.x * 2 * COLS + COLS + c] = q;
    }
  }
}

// sum partials over blocks -> SUM/SQ.  One block per output element j in
// [0, 2*width); 256 threads stride over nb partials, wave+LDS reduce.
__global__ __launch_bounds__(256) void k_red(const float* __restrict__ part, int nb,
                                             int width, float* __restrict__ outSum,
                                             float* __restrict__ outSq) {
  const int j = blockIdx.x;  // 0 .. 2*width-1
  float a = 0.f;
  for (int b = threadIdx.x; b < nb; b += 256)
    a += part[(size_t)b * 2 * width + j];
  a += __shfl_xor(a, 1);  a += __shfl_xor(a, 2);  a += __shfl_xor(a, 4);
  a += __shfl_xor(a, 8);  a += __shfl_xor(a, 16); a += __shfl_xor(a, 32);
  __shared__ float red[4];
  const int lane = threadIdx.x & 63, wv = threadIdx.x >> 6;
  if (lane == 0) red[wv] = a;
  __syncthreads();
  if (threadIdx.x == 0) {
    float s = red[0] + red[1] + red[2] + red[3];
    if (j < width) outSum[j] = s;
    else outSq[j - width] = s;
  }
}

// ---------------- graph pooling ----------------

DEV void k_pool(const float* __restrict__ hv, const int* __restrict__ batch,
                const float* __restrict__ vn, float* __restrict__ vt) {
  int g = blockIdx.x;
  int lo = 0, hi = NN;
  while (lo < hi) { int mid = (lo + hi) >> 1; if (batch[mid] < g) lo = mid + 1; else hi = mid; }
  int s = lo;
  hi = NN;
  while (lo < hi) { int mid = (lo + hi) >> 1; if (batch[mid] < g + 1) lo = mid + 1; else hi = mid; }
  int e = lo;
  int ry = threadIdx.x >> 5, cx = threadIdx.x & 31;
  float4 acc = make_float4(0.f, 0.f, 0.f, 0.f);
  for (int n = s + ry; n < e; n += 8) {
    float4 v = *(const float4*)(hv + (size_t)n * D + cx * 4);
    acc.x += v.x; acc.y += v.y; acc.z += v.z; acc.w += v.w;
  }
  __shared__ float4 red[8][32];
  red[ry][cx] = acc;
  __syncthreads();
  for (int st = 4; st >= 1; st >>= 1) {
    if (ry < st) {
      float4 o = red[ry + st][cx];
      red[ry][cx].x += o.x; red[ry][cx].y += o.y;
      red[ry][cx].z += o.z; red[ry][cx].w += o.w;
    }
    __syncthreads();
  }
  if (ry == 0) {
    float4 v = red[0][cx];
    float4 b = *(const float4*)(vn + (size_t)g * D + cx * 4);
    v.x += b.x; v.y += b.y; v.z += b.z; v.w += b.w;
    *(float4*)(vt + (size_t)g * D + cx * 4) = v;
  }
}

// ---------------- launcher ----------------

extern "C" void kernel_launch(void* const* d_in, const int* in_sizes, int n_in,
                              void* d_out, int out_size, void* d_ws, size_t ws_size,
                              hipStream_t stream) {
  const int* x = (const int*)d_in[0];
  const int* ei = (const int*)d_in[1];
  const int* eattr = (const int*)d_in[2];
  const int* batch = (const int*)d_in[3];
  const float* atom_emb = (const float*)d_in[4];
  const float* bond_emb = (const float*)d_in[5];
  const float* eps = (const float*)d_in[6];
  const float* conv_w1 = (const float*)d_in[7];
  const float* conv_b1 = (const float*)d_in[8];
  const float* conv_bn_g = (const float*)d_in[9];
  const float* conv_bn_b = (const float*)d_in[10];
  const float* conv_w2 = (const float*)d_in[11];
  const float* conv_b2 = (const float*)d_in[12];
  const float* bn_g = (const float*)d_in[13];
  const float* bn_b = (const float*)d_in[14];
  const float* vn_emb = (const float*)d_in[15];
  const float* vn_w1 = (const float*)d_in[16];
  const float* vn_b1 = (const float*)d_in[17];
  const float* vn_bn1_g = (const float*)d_in[18];
  const float* vn_bn1_b = (const float*)d_in[19];
  const float* vn_w2 = (const float*)d_in[20];
  const float* vn_b2 = (const float*)d_in[21];
  const float* vn_bn2_g = (const float*)d_in[22];
  const float* vn_bn2_b = (const float*)d_in[23];
  float* out = (float*)d_out;

  char* w = (char*)d_ws;
  auto alloc = [&](size_t bytes) {
    char* p = w;
    w += (bytes + 255) & ~((size_t)255);
    return p;
  };
  float* h   = (float*)alloc((size_t)NN * D * 4);     // z buffer (mgemm2 out)
  float* hv  = (float*)alloc((size_t)NN * D * 4);
  ushort* y  = (ushort*)alloc((size_t)NN * 256 * 2);  // bf16 intermediate
  unsigned* Ahi = (unsigned*)alloc((size_t)NN * 64 * 4);  // A' bf16 hi plane
  unsigned* Alo = (unsigned*)alloc((size_t)NN * 64 * 4);  // A' bf16 lo plane
  float* vn  = (float*)alloc((size_t)NG * D * 4);
  float* vt  = (float*)alloc((size_t)NG * D * 4);
  ushort* yv = (ushort*)alloc((size_t)NG * 256 * 2);
  float* zv  = (float*)alloc((size_t)NG * D * 4);
  float* stats = (float*)alloc(16 * 512 * 4);  // slots of (sum[256],sq[256])
  auto SUM = [&](int slot) { return stats + slot * 512; };
  auto SQ  = [&](int slot) { return stats + slot * 512 + 256; };
  const int gx = (NN + 127) / 128;  // 391
  const int gv = (NG + 127) / 128;  // 4
  float* partA = (float*)alloc((size_t)gx * 512 * 4);
  float* partB = (float*)alloc((size_t)gx * 256 * 4);
  int* cnt = (int*)alloc((size_t)NN * 4);
  int* rowptr = (int*)alloc((size_t)(NN + 1) * 4);
  int* cursor = (int*)alloc((size_t)NN * 4);
  unsigned* csr = (unsigned*)alloc((size_t)NE * 4);
  int* bsum = (int*)alloc(128 * 4);
  ushort* wt1h = (ushort*)alloc((size_t)NL * 256 * 128 * 2);
  ushort* wt1l = (ushort*)alloc((size_t)NL * 256 * 128 * 2);
  ushort* wt2h = (ushort*)alloc((size_t)NL * 128 * 256 * 2);
  ushort* wt2l = (ushort*)alloc((size_t)NL * 128 * 256 * 2);
  ushort* vw1h = (ushort*)alloc((size_t)2 * 256 * 128 * 2);
  ushort* vw1l = (ushort*)alloc((size_t)2 * 256 * 128 * 2);
  ushort* vw2h = (ushort*)alloc((size_t)2 * 128 * 256 * 2);
  ushort* vw2l = (ushort*)alloc((size_t)2 * 128 * 256 * 2);

  // zero the atomic stat slots (vn path only)
  hipMemsetAsync(stats, 0, 16 * 512 * 4, stream);

  // all weight transposes + splits in one launch
  k_cvtw_all<<<dim3(128, 10), 256, 0, stream>>>(
      conv_w1, conv_w2, vn_w1, vn_w2, wt1h, wt1l, wt2h, wt2l,
      vw1h, vw1l, vw2h, vw2l);

  // encoders (atom + vn broadcast) and vn buffer init, one launch
  k_atomvn<<<NB_ATOM + NB_VNI, 256, 0, stream>>>(x, atom_emb, vn_emb, hv, vn);

  // CSR build (reused by all 3 layers)
  hipMemsetAsync(cnt, 0, (size_t)NN * 4, stream);
  k_hist<<<(NE + 255) / 256, 256, 0, stream>>>(ei, cnt);
  k_scan_a<<<NBLK, SCAN_B, 0, stream>>>(cnt, rowptr, bsum);
  k_scan_c<<<NBLK, SCAN_B, 0, stream>>>(rowptr, bsum);
  (void)hipMemcpyAsync(cursor, rowptr, (size_t)NN * 4, hipMemcpyDeviceToDevice, stream);
  k_fill<<<(NE + 255) / 256, 256, 0, stream>>>(ei, eattr, cursor, csr);

  for (int l = 0; l < NL; ++l) {
    const int sc1 = l, sc2 = 3 + l, sv1 = 6 + l, sv2 = 8 + l;
    k_agg<<<(NN * 64 + 255) / 256, 256, 0, stream>>>(
        hv, csr, rowptr, bond_emb + (size_t)l * 3 * 8 * D, eps + l, Ahi, Alo);

    k_mgemm<3, 256, 512, false, true><<<gx, 512, 0, stream>>>(
        NN, 128, nullptr, (const ushort*)Ahi, (const ushort*)Alo,
        nullptr, nullptr, nullptr, nullptr, 0.f,
        wt1h + (size_t)l * 256 * 128, wt1l + (size_t)l * 256 * 128,
        conv_b1 + l * 256, nullptr, y, nullptr, nullptr, partA);
    k_red<<<512, 256, 0, stream>>>(partA, gx, 256, SUM(sc1), SQ(sc1));
    k_mgemm<2, 128, 256, false, false><<<gx, 256, 0, stream>>>(
        NN, 256, nullptr, y, nullptr, SUM(sc1), SQ(sc1),
        conv_bn_g + l * 256, conv_bn_b + l * 256, 1.f / NN,
        wt2h + (size_t)l * 128 * 256, wt2l + (size_t)l * 128 * 256,
        conv_b2 + l * 128, h, nullptr, nullptr, nullptr, partB);
    k_red<<<256, 256, 0, stream>>>(partB, gx, 128, SUM(sc2), SQ(sc2));

    if (l < NL - 1) {
      k_pool<<<NG, 256, 0, stream>>>(hv, batch, vn, vt);
      k_mgemm<0, 256, 512, true, true><<<gv, 512, 0, stream>>>(
          NG, 128, vt, nullptr, nullptr, nullptr, nullptr, nullptr, nullptr, 0.f,
          vw1h + (size_t)l * 256 * 128, vw1l + (size_t)l * 256 * 128,
          vn_b1 + l * 256, nullptr, yv, SUM(sv1), SQ(sv1), nullptr);
      k_mgemm<2, 128, 256, true, false><<<gv, 256, 0, stream>>>(
          NG, 256, nullptr, yv, nullptr, SUM(sv1), SQ(sv1),
          vn_bn1_g + l * 256, vn_bn1_b + l * 256, 1.f / NG,
          vw2h + (size_t)l * 128 * 256, vw2l + (size_t)l * 128 * 256,
          vn_b2 + l * 128, zv, nullptr, SUM(sv2), SQ(sv2), nullptr);
      // vn = relu(bn2(zv))
      k_post<<<(NG * 32 + 255) / 256, 256, 0, stream>>>(
          zv, SUM(sv2), SQ(sv2), vn_bn2_g + l * 128, vn_bn2_b + l * 128,
          1.f / NG, nullptr, nullptr, vn, NG, 1);
      // hv_next = relu(bn(z)) + vn_new[batch]
      k_post<<<(NN * 32 + 255) / 256, 256, 0, stream>>>(
          h, SUM(sc2), SQ(sc2), bn_g + l * 128, bn_b + l * 128,
          1.f / NN, vn, batch, hv, NN, 1);
    } else {
      // final output: bn(z), no relu
      k_post<<<(NN * 32 + 255) / 256, 256, 0, stream>>>(
          h, SUM(sc2), SQ(sc2), bn_g + l * 128, bn_b + l * 128,
          1.f / NN, nullptr, nullptr, out, NN, 0);
    }
  }
}

// Round 16
// 772.802 us; speedup vs baseline: 1.7822x; 1.0273x over previous
//
#include <hip/hip_runtime.h>

#define DEV __global__ __launch_bounds__(256)

constexpr int NN = 50000;   // nodes
constexpr int NE = 600000;  // edges
constexpr int D  = 128;     // emb dim
constexpr int NG = 500;     // graphs
constexpr int NL = 3;       // layers
constexpr int SCAN_B = 512;
constexpr int NBLK = (NN + SCAN_B - 1) / SCAN_B;  // 98

typedef __attribute__((ext_vector_type(8))) short bf16x8;
typedef __attribute__((ext_vector_type(4))) float f32x4;

__device__ inline ushort f2bf(float f) {
  unsigned u = __builtin_bit_cast(unsigned, f);
  unsigned r = u + 0x7FFFu + ((u >> 16) & 1u);
  return (ushort)(r >> 16);
}
__device__ inline float bf2f(ushort h) {
  unsigned u = ((unsigned)h) << 16;
  return __builtin_bit_cast(float, u);
}

// ---------------- encoders / elementwise ----------------

// blocks [0, NB_ATOM): hv0[n][d] = sum_i atom_emb[i][x[n][i]][d] + vn_emb[d]
// blocks [NB_ATOM, ..): vn[g] = vn_emb
constexpr int NB_ATOM = (NN * 32 + 255) / 256;  // 6250
constexpr int NB_VNI  = (NG * 32 + 255) / 256;  // 63
DEV void k_atomvn(const int* __restrict__ x, const float* __restrict__ emb,
                  const float* __restrict__ vne, float* __restrict__ hv,
                  ushort* __restrict__ hvb, float* __restrict__ vn) {
  if ((int)blockIdx.x >= NB_ATOM) {
    int t = (blockIdx.x - NB_ATOM) * 256 + threadIdx.x;
    int g = t >> 5, c = (t & 31) * 4;
    if (g < NG) *(float4*)(vn + (size_t)g * D + c) = *(const float4*)(vne + c);
    return;
  }
  int t = blockIdx.x * 256 + threadIdx.x;
  int n = t >> 5, c = (t & 31) * 4;
  if (n >= NN) return;
  float4 acc = *(const float4*)(vne + c);
  #pragma unroll
  for (int i = 0; i < 9; ++i) {
    int v = x[n * 9 + i];
    float4 e = *(const float4*)(emb + ((size_t)(i * 128 + v)) * D + c);
    acc.x += e.x; acc.y += e.y; acc.z += e.z; acc.w += e.w;
  }
  *(float4*)(hv + (size_t)n * D + c) = acc;
  ushort4 hb;
  hb.x = f2bf(acc.x); hb.y = f2bf(acc.y);
  hb.z = f2bf(acc.z); hb.w = f2bf(acc.w);
  *(ushort4*)(hvb + (size_t)n * D + c) = hb;
}

// dst = bn(z) [+relu] [+ vnadd[batch]]; optionally also write bf16 plane
DEV void k_post(const float* __restrict__ z, const float* __restrict__ sum,
                const float* __restrict__ sq, const float* __restrict__ gam,
                const float* __restrict__ bet, float invM,
                const float* __restrict__ vnadd, const int* __restrict__ batch,
                float* __restrict__ dst, ushort* __restrict__ dstb,
                int M, int relu) {
  int t = blockIdx.x * 256 + threadIdx.x;
  int n = t >> 5, c = (t & 31) * 4;
  if (n >= M) return;
  f32x4 s = *(const f32x4*)(sum + c);
  f32x4 q = *(const f32x4*)(sq + c);
  f32x4 g = *(const f32x4*)(gam + c);
  f32x4 b = *(const f32x4*)(bet + c);
  f32x4 v = *(const f32x4*)(z + (size_t)n * 128 + c);
  f32x4 o;
  #pragma unroll
  for (int j = 0; j < 4; ++j) {
    float mu = s[j] * invM;
    float var = q[j] * invM - mu * mu;
    float sc = g[j] * rsqrtf(var + 1e-5f);
    float sh = b[j] - mu * sc;
    o[j] = fmaf(v[j], sc, sh);
    if (relu) o[j] = fmaxf(o[j], 0.f);
  }
  if (vnadd) {
    f32x4 a = *(const f32x4*)(vnadd + (size_t)batch[n] * 128 + c);
    #pragma unroll
    for (int j = 0; j < 4; ++j) o[j] += a[j];
  }
  *(f32x4*)(dst + (size_t)n * 128 + c) = o;
  if (dstb) {
    ushort4 hb;
    hb.x = f2bf(o[0]); hb.y = f2bf(o[1]);
    hb.z = f2bf(o[2]); hb.w = f2bf(o[3]);
    *(ushort4*)(dstb + (size_t)n * 128 + c) = hb;
  }
}

// ---------------- CSR build ----------------

DEV void k_hist(const int* __restrict__ ei, int* __restrict__ cnt) {
  int e = blockIdx.x * 256 + threadIdx.x;
  if (e < NE) atomicAdd(&cnt[ei[NE + e]], 1);
}

__global__ __launch_bounds__(SCAN_B) void k_scan_a(const int* __restrict__ cnt,
                                                   int* __restrict__ rowptr,
                                                   int* __restrict__ bsum) {
  __shared__ int sh[SCAN_B];
  int i = blockIdx.x * SCAN_B + threadIdx.x;
  int v = (i < NN) ? cnt[i] : 0;
  sh[threadIdx.x] = v;
  __syncthreads();
  for (int off = 1; off < SCAN_B; off <<= 1) {
    int u = (threadIdx.x >= (unsigned)off) ? sh[threadIdx.x - off] : 0;
    __syncthreads();
    sh[threadIdx.x] += u;
    __syncthreads();
  }
  if (i < NN) rowptr[i + 1] = sh[threadIdx.x];
  if (threadIdx.x == SCAN_B - 1) bsum[blockIdx.x] = sh[SCAN_B - 1];
}

// adds exclusive prefix of block totals (bsum holds raw block totals)
__global__ __launch_bounds__(SCAN_B) void k_scan_c(int* __restrict__ rowptr,
                                                   const int* __restrict__ bsum) {
  __shared__ int off;
  if (threadIdx.x == 0) {
    int a = 0;
    for (int b = 0; b < (int)blockIdx.x; ++b) a += bsum[b];
    off = a;
  }
  __syncthreads();
  int i = blockIdx.x * SCAN_B + threadIdx.x;
  if (i < NN) rowptr[i + 1] += off;
  if (i == 0) rowptr[0] = 0;
}

DEV void k_fill(const int* __restrict__ ei, const int* __restrict__ eattr,
                int* __restrict__ cursor, unsigned* __restrict__ csr) {
  int e = blockIdx.x * 256 + threadIdx.x;
  if (e >= NE) return;
  int dn = ei[NE + e];
  int p = atomicAdd(&cursor[dn], 1);
  unsigned a0 = (unsigned)eattr[e * 3 + 0];
  unsigned a1 = (unsigned)eattr[e * 3 + 1];
  unsigned a2 = (unsigned)eattr[e * 3 + 2];
  csr[p] = (unsigned)ei[e] | (a0 << 17) | (a1 << 20) | (a2 << 23);
}

// ---- edge aggregation (wave per node) + fused A' = (1+eps)*hv + agg,
//      gathers neighbor rows from the bf16 plane (half the bytes);
//      self-term from exact fp32 hv; writes pre-split bf16 hi/lo planes ----

DEV void k_agg(const float* __restrict__ hv, const ushort* __restrict__ hvb,
               const unsigned* __restrict__ csr, const int* __restrict__ rowptr,
               const float* __restrict__ bond, const float* __restrict__ epsp,
               unsigned* __restrict__ Ahi, unsigned* __restrict__ Alo) {
  __shared__ float eb[3 * 8 * D];
  for (int i = threadIdx.x; i < 3 * 8 * D; i += 256) eb[i] = bond[i];
  __syncthreads();
  int wid = (blockIdx.x * 256 + threadIdx.x) >> 6;
  int lane = threadIdx.x & 63;
  if (wid >= NN) return;
  int d0 = lane * 2;
  float ax = 0.f, ay = 0.f;
  int p = rowptr[wid];
  const int p1 = rowptr[wid + 1];
  for (; p + 4 <= p1; p += 4) {
    unsigned pk[4];
    #pragma unroll
    for (int j = 0; j < 4; ++j) pk[j] = csr[p + j];
    ushort2 hvv[4];
    #pragma unroll
    for (int j = 0; j < 4; ++j)
      hvv[j] = *(const ushort2*)(hvb + (size_t)(pk[j] & 0x1FFFF) * D + d0);
    #pragma unroll
    for (int j = 0; j < 4; ++j) {
      float2 e0 = *(const float2*)(eb + (((pk[j] >> 17) & 7u)) * D + d0);
      float2 e1 = *(const float2*)(eb + (8 + ((pk[j] >> 20) & 7u)) * D + d0);
      float2 e2 = *(const float2*)(eb + (16 + ((pk[j] >> 23) & 7u)) * D + d0);
      ax += fmaxf(bf2f(hvv[j].x) + e0.x + e1.x + e2.x, 0.f);
      ay += fmaxf(bf2f(hvv[j].y) + e0.y + e1.y + e2.y, 0.f);
    }
  }
  for (; p < p1; ++p) {
    unsigned pk = csr[p];
    ushort2 hvv = *(const ushort2*)(hvb + (size_t)(pk & 0x1FFFF) * D + d0);
    float2 e0 = *(const float2*)(eb + (((pk >> 17) & 7u)) * D + d0);
    float2 e1 = *(const float2*)(eb + (8 + ((pk >> 20) & 7u)) * D + d0);
    float2 e2 = *(const float2*)(eb + (16 + ((pk >> 23) & 7u)) * D + d0);
    ax += fmaxf(bf2f(hvv.x) + e0.x + e1.x + e2.x, 0.f);
    ay += fmaxf(bf2f(hvv.y) + e0.y + e1.y + e2.y, 0.f);
  }
  // fused mgemm1 prologue: A' = (1+eps)*hv + agg, split exact bf16 hi/lo
  float2 hvo = *(const float2*)(hv + (size_t)wid * D + d0);
  float ef = 1.f + epsp[0];
  float a0 = fmaf(ef, hvo.x, ax);
  float a1 = fmaf(ef, hvo.y, ay);
  ushort h0 = f2bf(a0), h1 = f2bf(a1);
  ushort l0 = f2bf(a0 - bf2f(h0)), l1 = f2bf(a1 - bf2f(h1));
  Ahi[(size_t)wid * 64 + lane] = (unsigned)h0 | ((unsigned)h1 << 16);
  Alo[(size_t)wid * 64 + lane] = (unsigned)l0 | ((unsigned)l1 << 16);
}

// ---------------- weight transpose + bf16 hi/lo split (all weights, 1 kernel) ----
// seg 0-2: conv_w1[l], 3-5: conv_w2[l], 6-7: vn_w1[l], 8-9: vn_w2[l]
__global__ __launch_bounds__(256) void k_cvtw_all(
    const float* __restrict__ w1, const float* __restrict__ w2,
    const float* __restrict__ v1, const float* __restrict__ v2,
    ushort* __restrict__ t1h, ushort* __restrict__ t1l,
    ushort* __restrict__ t2h, ushort* __restrict__ t2l,
    ushort* __restrict__ u1h, ushort* __restrict__ u1l,
    ushort* __restrict__ u2h, ushort* __restrict__ u2l) {
  int seg = blockIdx.y;
  const float* src; ushort *th, *tl; int K, lognc, idx;
  if (seg < 3)      { src = w1; th = t1h; tl = t1l; K = 128; lognc = 8; idx = seg; }
  else if (seg < 6) { src = w2; th = t2h; tl = t2l; K = 256; lognc = 7; idx = seg - 3; }
  else if (seg < 8) { src = v1; th = u1h; tl = u1l; K = 128; lognc = 8; idx = seg - 6; }
  else              { src = v2; th = u2h; tl = u2l; K = 256; lognc = 7; idx = seg - 8; }
  size_t base = (size_t)idx * (K << lognc);
  int i = blockIdx.x * 256 + threadIdx.x;
  if (i >= (K << lognc)) return;
  int k = i >> lognc, c = i & ((1 << lognc) - 1);
  float v = src[base + i];
  ushort hi = f2bf(v);
  th[base + (size_t)c * K + k] = hi;
  tl[base + (size_t)c * K + k] = f2bf(v - bf2f(hi));
}

// ---------------- MFMA bf16x3 GEMM + BN-stats epilogue ----------------
// Y[M x COLS] = A' @ Wt^T + bias
//   AMODE 0: A' = A0 (fp32, split on the fly)
//   AMODE 2: A' = relu(bf2f(Abh[..]) * bnscale[k] + bnshift[k])  (bf16 input)
//   AMODE 3: A' pre-split bf16 planes Abh/Abl (pure copy staging)
// Output: OUTBF ? Yb (bf16, round-nearest) : Yf (fp32). Stats from exact fp32.
// Stats: ATOMIC -> atomicAdd into colsum/colsq; else per-block partials.
template <int AMODE, int COLS, int NT, bool ATOMIC, bool OUTBF>
__global__ __launch_bounds__(NT) void k_mgemm(
    int M, int K, const float* __restrict__ A0, const ushort* __restrict__ Abh,
    const ushort* __restrict__ Abl, const float* __restrict__ bnsum,
    const float* __restrict__ bnsq, const float* __restrict__ bngam,
    const float* __restrict__ bnbet, float invPrevM,
    const ushort* __restrict__ Wth, const ushort* __restrict__ Wtl,
    const float* __restrict__ bias, float* __restrict__ Yf,
    ushort* __restrict__ Yb, float* __restrict__ colsum,
    float* __restrict__ colsq, float* __restrict__ partial) {
  constexpr int NWC = COLS / 64;
  __shared__ __align__(16) ushort Ah[4][128][8];
  __shared__ __align__(16) ushort Al[4][128][8];
  __shared__ __align__(16) ushort Bh[4][COLS][8];
  __shared__ __align__(16) ushort Bl[4][COLS][8];
  __shared__ float bnsc[AMODE == 2 ? 256 : 1];
  __shared__ float bnsh[AMODE == 2 ? 256 : 1];
  const int tid = threadIdx.x;
  const int row0 = blockIdx.x * 128;
  const int lane = tid & 63, w = tid >> 6;
  const int wr = w / NWC, wc = w % NWC;
  const int kc = lane >> 4, lr = lane & 15;

  if (AMODE == 2) {
    for (int c = tid; c < K; c += NT) {
      float mu = bnsum[c] * invPrevM;
      float var = bnsq[c] * invPrevM - mu * mu;
      float sc = bngam[c] * rsqrtf(var + 1e-5f);
      bnsc[c] = sc;
      bnsh[c] = bnbet[c] - mu * sc;
    }
    __syncthreads();
  }

  f32x4 acc[4][4] = {};

  for (int k0 = 0; k0 < K; k0 += 32) {
    // ---- stage A' ----
    for (int i = tid; i < 512; i += NT) {
      const int c = i >> 7, r = i & 127;
      const int gk = k0 + c * 8;
      const int gr = row0 + r;
      if (AMODE == 3) {
        uint4 vh = make_uint4(0, 0, 0, 0), vl = make_uint4(0, 0, 0, 0);
        if (gr < M) {
          vh = *(const uint4*)(Abh + (size_t)gr * K + gk);
          vl = *(const uint4*)(Abl + (size_t)gr * K + gk);
        }
        *(uint4*)&Ah[c][r][0] = vh;
        *(uint4*)&Al[c][r][0] = vl;
      } else {
        float v[8];
        if (gr < M) {
          if (AMODE == 2) {
            alignas(16) ushort yq[8];
            *(uint4*)yq = *(const uint4*)(Abh + (size_t)gr * K + gk);
            #pragma unroll
            for (int j = 0; j < 8; ++j)
              v[j] = fmaxf(fmaf(bf2f(yq[j]), bnsc[gk + j], bnsh[gk + j]), 0.f);
          } else {
            f32x4 a0 = *(const f32x4*)(A0 + (size_t)gr * K + gk);
            f32x4 a1 = *(const f32x4*)(A0 + (size_t)gr * K + gk + 4);
            #pragma unroll
            for (int j = 0; j < 4; ++j) { v[j] = a0[j]; v[4 + j] = a1[j]; }
          }
        } else {
          #pragma unroll
          for (int j = 0; j < 8; ++j) v[j] = 0.f;
        }
        alignas(16) ushort th[8], tl[8];
        #pragma unroll
        for (int j = 0; j < 8; ++j) {
          ushort hi = f2bf(v[j]);
          th[j] = hi;
          tl[j] = f2bf(v[j] - bf2f(hi));
        }
        *(uint4*)&Ah[c][r][0] = *(const uint4*)th;
        *(uint4*)&Al[c][r][0] = *(const uint4*)tl;
      }
    }
    // ---- stage B ----
    for (int i = tid; i < COLS * 4; i += NT) {
      const int c = i / COLS, r = i % COLS;
      const int gk = k0 + c * 8;
      *(uint4*)&Bh[c][r][0] = *(const uint4*)(Wth + (size_t)r * K + gk);
      *(uint4*)&Bl[c][r][0] = *(const uint4*)(Wtl + (size_t)r * K + gk);
    }
    __syncthreads();
    // ---- MFMA: 3-term bf16 emulation of fp32 ----
    bf16x8 bhf[4], blf[4];
    #pragma unroll
    for (int fc = 0; fc < 4; ++fc) {
      bhf[fc] = *(const bf16x8*)&Bh[kc][wc * 64 + fc * 16 + lr][0];
      blf[fc] = *(const bf16x8*)&Bl[kc][wc * 64 + fc * 16 + lr][0];
    }
    #pragma unroll
    for (int fr = 0; fr < 4; ++fr) {
      bf16x8 ahf = *(const bf16x8*)&Ah[kc][wr * 64 + fr * 16 + lr][0];
      bf16x8 alf = *(const bf16x8*)&Al[kc][wr * 64 + fr * 16 + lr][0];
      #pragma unroll
      for (int fc = 0; fc < 4; ++fc) {
        acc[fr][fc] = __builtin_amdgcn_mfma_f32_16x16x32_bf16(ahf, bhf[fc], acc[fr][fc], 0, 0, 0);
        acc[fr][fc] = __builtin_amdgcn_mfma_f32_16x16x32_bf16(alf, bhf[fc], acc[fr][fc], 0, 0, 0);
        acc[fr][fc] = __builtin_amdgcn_mfma_f32_16x16x32_bf16(ahf, blf[fc], acc[fr][fc], 0, 0, 0);
      }
    }
    __syncthreads();
  }

  // ---- epilogue: bias, store, block-level column stats (no global atomics) ----
  float* sred = reinterpret_cast<float*>(&Ah[0][0][0]);  // [2][COLS] (Ah is dead)
  float* qred = sred + 2 * COLS;
  #pragma unroll
  for (int fc = 0; fc < 4; ++fc) {
    const int gc = wc * 64 + fc * 16 + lr;
    const float bb = bias[gc];
    float cs = 0.f, cq = 0.f;
    #pragma unroll
    for (int fr = 0; fr < 4; ++fr) {
      const int rb = row0 + wr * 64 + fr * 16 + kc * 4;
      #pragma unroll
      for (int rg = 0; rg < 4; ++rg) {
        int gr = rb + rg;
        if (gr < M) {
          float v = acc[fr][fc][rg] + bb;
          if (OUTBF) Yb[(size_t)gr * COLS + gc] = f2bf(v);
          else       Yf[(size_t)gr * COLS + gc] = v;
          cs += v;
          cq += v * v;
        }
      }
    }
    cs += __shfl_xor(cs, 16); cs += __shfl_xor(cs, 32);
    cq += __shfl_xor(cq, 16); cq += __shfl_xor(cq, 32);
    if (kc == 0) {
      sred[wr * COLS + gc] = cs;
      qred[wr * COLS + gc] = cq;
    }
  }
  __syncthreads();
  for (int c = tid; c < COLS; c += NT) {
    float s = sred[c] + sred[COLS + c];
    float q = qred[c] + qred[COLS + c];
    if (ATOMIC) {
      atomicAdd(&colsum[c], s);
      atomicAdd(&colsq[c], q);
    } else {
      partial[(size_t)blockIdx.x * 2 * COLS + c] = s;
      partial[(size_t)blockIdx.x * 2 * COLS + COLS + c] = q;
    }
  }
}

// sum partials over blocks -> SUM/SQ.  One block per output element j in
// [0, 2*width); 256 threads stride over nb partials, wave+LDS reduce.
__global__ __launch_bounds__(256) void k_red(const float* __restrict__ part, int nb,
                                             int width, float* __restrict__ outSum,
                                             float* __restrict__ outSq) {
  const int j = blockIdx.x;  // 0 .. 2*width-1
  float a = 0.f;
  for (int b = threadIdx.x; b < nb; b += 256)
    a += part[(size_t)b * 2 * width + j];
  a += __shfl_xor(a, 1);  a += __shfl_xor(a, 2);  a += __shfl_xor(a, 4);
  a += __shfl_xor(a, 8);  a += __shfl_xor(a, 16); a += __shfl_xor(a, 32);
  __shared__ float red[4];
  const int lane = threadIdx.x & 63, wv = threadIdx.x >> 6;
  if (lane == 0) red[wv] = a;
  __syncthreads();
  if (threadIdx.x == 0) {
    float s = red[0] + red[1] + red[2] + red[3];
    if (j < width) outSum[j] = s;
    else outSq[j - width] = s;
  }
}

// ---------------- graph pooling ----------------

DEV void k_pool(const float* __restrict__ hv, const int* __restrict__ batch,
                const float* __restrict__ vn, float* __restrict__ vt) {
  int g = blockIdx.x;
  int lo = 0, hi = NN;
  while (lo < hi) { int mid = (lo + hi) >> 1; if (batch[mid] < g) lo = mid + 1; else hi = mid; }
  int s = lo;
  hi = NN;
  while (lo < hi) { int mid = (lo + hi) >> 1; if (batch[mid] < g + 1) lo = mid + 1; else hi = mid; }
  int e = lo;
  int ry = threadIdx.x >> 5, cx = threadIdx.x & 31;
  float4 acc = make_float4(0.f, 0.f, 0.f, 0.f);
  for (int n = s + ry; n < e; n += 8) {
    float4 v = *(const float4*)(hv + (size_t)n * D + cx * 4);
    acc.x += v.x; acc.y += v.y; acc.z += v.z; acc.w += v.w;
  }
  __shared__ float4 red[8][32];
  red[ry][cx] = acc;
  __syncthreads();
  for (int st = 4; st >= 1; st >>= 1) {
    if (ry < st) {
      float4 o = red[ry + st][cx];
      red[ry][cx].x += o.x; red[ry][cx].y += o.y;
      red[ry][cx].z += o.z; red[ry][cx].w += o.w;
    }
    __syncthreads();
  }
  if (ry == 0) {
    float4 v = red[0][cx];
    float4 b = *(const float4*)(vn + (size_t)g * D + cx * 4);
    v.x += b.x; v.y += b.y; v.z += b.z; v.w += b.w;
    *(float4*)(vt + (size_t)g * D + cx * 4) = v;
  }
}

// ---------------- launcher ----------------

extern "C" void kernel_launch(void* const* d_in, const int* in_sizes, int n_in,
                              void* d_out, int out_size, void* d_ws, size_t ws_size,
                              hipStream_t stream) {
  const int* x = (const int*)d_in[0];
  const int* ei = (const int*)d_in[1];
  const int* eattr = (const int*)d_in[2];
  const int* batch = (const int*)d_in[3];
  const float* atom_emb = (const float*)d_in[4];
  const float* bond_emb = (const float*)d_in[5];
  const float* eps = (const float*)d_in[6];
  const float* conv_w1 = (const float*)d_in[7];
  const float* conv_b1 = (const float*)d_in[8];
  const float* conv_bn_g = (const float*)d_in[9];
  const float* conv_bn_b = (const float*)d_in[10];
  const float* conv_w2 = (const float*)d_in[11];
  const float* conv_b2 = (const float*)d_in[12];
  const float* bn_g = (const float*)d_in[13];
  const float* bn_b = (const float*)d_in[14];
  const float* vn_emb = (const float*)d_in[15];
  const float* vn_w1 = (const float*)d_in[16];
  const float* vn_b1 = (const float*)d_in[17];
  const float* vn_bn1_g = (const float*)d_in[18];
  const float* vn_bn1_b = (const float*)d_in[19];
  const float* vn_w2 = (const float*)d_in[20];
  const float* vn_b2 = (const float*)d_in[21];
  const float* vn_bn2_g = (const float*)d_in[22];
  const float* vn_bn2_b = (const float*)d_in[23];
  float* out = (float*)d_out;

  char* w = (char*)d_ws;
  auto alloc = [&](size_t bytes) {
    char* p = w;
    w += (bytes + 255) & ~((size_t)255);
    return p;
  };
  float* h   = (float*)alloc((size_t)NN * D * 4);     // z buffer (mgemm2 out)
  float* hv  = (float*)alloc((size_t)NN * D * 4);
  ushort* hvb = (ushort*)alloc((size_t)NN * D * 2);   // bf16 shadow of hv (gathers)
  ushort* y  = (ushort*)alloc((size_t)NN * 256 * 2);  // bf16 intermediate
  unsigned* Ahi = (unsigned*)alloc((size_t)NN * 64 * 4);  // A' bf16 hi plane
  unsigned* Alo = (unsigned*)alloc((size_t)NN * 64 * 4);  // A' bf16 lo plane
  float* vn  = (float*)alloc((size_t)NG * D * 4);
  float* vt  = (float*)alloc((size_t)NG * D * 4);
  ushort* yv = (ushort*)alloc((size_t)NG * 256 * 2);
  float* zv  = (float*)alloc((size_t)NG * D * 4);
  float* stats = (float*)alloc(16 * 512 * 4);  // slots of (sum[256],sq[256])
  auto SUM = [&](int slot) { return stats + slot * 512; };
  auto SQ  = [&](int slot) { return stats + slot * 512 + 256; };
  const int gx = (NN + 127) / 128;  // 391
  const int gv = (NG + 127) / 128;  // 4
  float* partA = (float*)alloc((size_t)gx * 512 * 4);
  float* partB = (float*)alloc((size_t)gx * 256 * 4);
  int* cnt = (int*)alloc((size_t)NN * 4);
  int* rowptr = (int*)alloc((size_t)(NN + 1) * 4);
  int* cursor = (int*)alloc((size_t)NN * 4);
  unsigned* csr = (unsigned*)alloc((size_t)NE * 4);
  int* bsum = (int*)alloc(128 * 4);
  ushort* wt1h = (ushort*)alloc((size_t)NL * 256 * 128 * 2);
  ushort* wt1l = (ushort*)alloc((size_t)NL * 256 * 128 * 2);
  ushort* wt2h = (ushort*)alloc((size_t)NL * 128 * 256 * 2);
  ushort* wt2l = (ushort*)alloc((size_t)NL * 128 * 256 * 2);
  ushort* vw1h = (ushort*)alloc((size_t)2 * 256 * 128 * 2);
  ushort* vw1l = (ushort*)alloc((size_t)2 * 256 * 128 * 2);
  ushort* vw2h = (ushort*)alloc((size_t)2 * 128 * 256 * 2);
  ushort* vw2l = (ushort*)alloc((size_t)2 * 128 * 256 * 2);

  // zero the atomic stat slots (vn path only)
  hipMemsetAsync(stats, 0, 16 * 512 * 4, stream);

  // all weight transposes + splits in one launch
  k_cvtw_all<<<dim3(128, 10), 256, 0, stream>>>(
      conv_w1, conv_w2, vn_w1, vn_w2, wt1h, wt1l, wt2h, wt2l,
      vw1h, vw1l, vw2h, vw2l);

  // encoders (atom + vn broadcast) and vn buffer init, one launch
  k_atomvn<<<NB_ATOM + NB_VNI, 256, 0, stream>>>(x, atom_emb, vn_emb, hv, hvb, vn);

  // CSR build (reused by all 3 layers)
  hipMemsetAsync(cnt, 0, (size_t)NN * 4, stream);
  k_hist<<<(NE + 255) / 256, 256, 0, stream>>>(ei, cnt);
  k_scan_a<<<NBLK, SCAN_B, 0, stream>>>(cnt, rowptr, bsum);
  k_scan_c<<<NBLK, SCAN_B, 0, stream>>>(rowptr, bsum);
  (void)hipMemcpyAsync(cursor, rowptr, (size_t)NN * 4, hipMemcpyDeviceToDevice, stream);
  k_fill<<<(NE + 255) / 256, 256, 0, stream>>>(ei, eattr, cursor, csr);

  for (int l = 0; l < NL; ++l) {
    const int sc1 = l, sc2 = 3 + l, sv1 = 6 + l, sv2 = 8 + l;
    k_agg<<<(NN * 64 + 255) / 256, 256, 0, stream>>>(
        hv, hvb, csr, rowptr, bond_emb + (size_t)l * 3 * 8 * D, eps + l, Ahi, Alo);

    k_mgemm<3, 256, 512, false, true><<<gx, 512, 0, stream>>>(
        NN, 128, nullptr, (const ushort*)Ahi, (const ushort*)Alo,
        nullptr, nullptr, nullptr, nullptr, 0.f,
        wt1h + (size_t)l * 256 * 128, wt1l + (size_t)l * 256 * 128,
        conv_b1 + l * 256, nullptr, y, nullptr, nullptr, partA);
    k_red<<<512, 256, 0, stream>>>(partA, gx, 256, SUM(sc1), SQ(sc1));
    k_mgemm<2, 128, 256, false, false><<<gx, 256, 0, stream>>>(
        NN, 256, nullptr, y, nullptr, SUM(sc1), SQ(sc1),
        conv_bn_g + l * 256, conv_bn_b + l * 256, 1.f / NN,
        wt2h + (size_t)l * 128 * 256, wt2l + (size_t)l * 128 * 256,
        conv_b2 + l * 128, h, nullptr, nullptr, nullptr, partB);
    k_red<<<256, 256, 0, stream>>>(partB, gx, 128, SUM(sc2), SQ(sc2));

    if (l < NL - 1) {
      k_pool<<<NG, 256, 0, stream>>>(hv, batch, vn, vt);
      k_mgemm<0, 256, 512, true, true><<<gv, 512, 0, stream>>>(
          NG, 128, vt, nullptr, nullptr, nullptr, nullptr, nullptr, nullptr, 0.f,
          vw1h + (size_t)l * 256 * 128, vw1l + (size_t)l * 256 * 128,
          vn_b1 + l * 256, nullptr, yv, SUM(sv1), SQ(sv1), nullptr);
      k_mgemm<2, 128, 256, true, false><<<gv, 256, 0, stream>>>(
          NG, 256, nullptr, yv, nullptr, SUM(sv1), SQ(sv1),
          vn_bn1_g + l * 256, vn_bn1_b + l * 256, 1.f / NG,
          vw2h + (size_t)l * 128 * 256, vw2l + (size_t)l * 128 * 256,
          vn_b2 + l * 128, zv, nullptr, SUM(sv2), SQ(sv2), nullptr);
      // vn = relu(bn2(zv))
      k_post<<<(NG * 32 + 255) / 256, 256, 0, stream>>>(
          zv, SUM(sv2), SQ(sv2), vn_bn2_g + l * 128, vn_bn2_b + l * 128,
          1.f / NG, nullptr, nullptr, vn, nullptr, NG, 1);
      // hv_next = relu(bn(z)) + vn_new[batch]  (also refresh bf16 plane)
      k_post<<<(NN * 32 + 255) / 256, 256, 0, stream>>>(
          h, SUM(sc2), SQ(sc2), bn_g + l * 128, bn_b + l * 128,
          1.f / NN, vn, batch, hv, hvb, NN, 1);
    } else {
      // final output: bn(z), no relu
      k_post<<<(NN * 32 + 255) / 256, 256, 0, stream>>>(
          h, SUM(sc2), SQ(sc2), bn_g + l * 128, bn_b + l * 128,
          1.f / NN, nullptr, nullptr, out, nullptr, NN, 0);
    }
  }
}